// Round 1
// baseline (558.232 us; speedup 1.0000x reference)
//
#include <hip/hip_runtime.h>
#include <math.h>

#define DM 1024
#define DI 2048
#define NS 16
#define DTR 64
#define LL 2048
#define NXDBL 96      // DTR + 2*NS
#define NCHUNK 32
#define CHLEN 64      // LL / NCHUNK
#define KSPLIT 8
#define G2KC 256      // DI / KSPLIT

__device__ __forceinline__ float sigmoidf_(float x) { return 1.f / (1.f + __expf(-x)); }
__device__ __forceinline__ float siluf_(float x) { return x * sigmoidf_(x); }
__device__ __forceinline__ float softplusf_(float x) {
    return x > 0.f ? x + log1pf(__expf(-x)) : log1pf(__expf(x));
}

// ---------------- GEMM 128x128 tile, 8x8 microtile, BK=16 -----------------
// EPI==1: split output cols [0,DI) -> C0 (xc), [DI,2*DI) -> C1 (res), both ld=DI
template <int EPI>
__global__ __launch_bounds__(256) void gemm128(const float* __restrict__ A,
                                               const float* __restrict__ B,
                                               float* __restrict__ C0,
                                               float* __restrict__ C1,
                                               int M, int N, int K) {
    __shared__ float As[16][128];
    __shared__ float Bs[16][128];
    const int tid = threadIdx.x;
    const int bm = blockIdx.y * 128, bn = blockIdx.x * 128;
    const int ty = tid >> 4, tx = tid & 15;
    float acc[8][8];
#pragma unroll
    for (int i = 0; i < 8; i++)
#pragma unroll
        for (int j = 0; j < 8; j++) acc[i][j] = 0.f;

    const int ar = tid >> 2, ak = (tid & 3) << 2;
    const int bk = tid >> 5, bc = (tid & 31) << 2;

    for (int k0 = 0; k0 < K; k0 += 16) {
        float4 a0 = *(const float4*)&A[(size_t)(bm + ar) * K + k0 + ak];
        float4 a1 = *(const float4*)&A[(size_t)(bm + ar + 64) * K + k0 + ak];
        float4 b0 = *(const float4*)&B[(size_t)(k0 + bk) * N + bn + bc];
        float4 b1 = *(const float4*)&B[(size_t)(k0 + bk + 8) * N + bn + bc];
        __syncthreads();
        As[ak + 0][ar] = a0.x; As[ak + 1][ar] = a0.y;
        As[ak + 2][ar] = a0.z; As[ak + 3][ar] = a0.w;
        As[ak + 0][ar + 64] = a1.x; As[ak + 1][ar + 64] = a1.y;
        As[ak + 2][ar + 64] = a1.z; As[ak + 3][ar + 64] = a1.w;
        *(float4*)&Bs[bk][bc] = b0;
        *(float4*)&Bs[bk + 8][bc] = b1;
        __syncthreads();
#pragma unroll
        for (int k = 0; k < 16; k++) {
            float a[8], b[8];
            *(float4*)&a[0] = *(const float4*)&As[k][ty * 8];
            *(float4*)&a[4] = *(const float4*)&As[k][ty * 8 + 4];
            *(float4*)&b[0] = *(const float4*)&Bs[k][tx * 8];
            *(float4*)&b[4] = *(const float4*)&Bs[k][tx * 8 + 4];
#pragma unroll
            for (int i = 0; i < 8; i++)
#pragma unroll
                for (int j = 0; j < 8; j++) acc[i][j] = fmaf(a[i], b[j], acc[i][j]);
        }
    }
#pragma unroll
    for (int i = 0; i < 8; i++) {
        const int row = bm + ty * 8 + i;
#pragma unroll
        for (int j = 0; j < 8; j += 4) {
            const int col = bn + tx * 8 + j;
            float4 v = make_float4(acc[i][j], acc[i][j + 1], acc[i][j + 2], acc[i][j + 3]);
            if (EPI == 1) {
                if (col < DI)
                    *(float4*)&C0[(size_t)row * DI + col] = v;
                else
                    *(float4*)&C1[(size_t)row * DI + col - DI] = v;
            } else {
                *(float4*)&C0[(size_t)row * N + col] = v;
            }
        }
    }
}

// ---------------- GEMM 64x64 tile, 4x4 microtile, BK=16 -----------------
// EPI==0: plain C = A@B ; EPI==2: C = softplus(A@B + bias[col])
template <int EPI>
__global__ __launch_bounds__(256) void gemm64(const float* __restrict__ A,
                                              const float* __restrict__ B,
                                              const float* __restrict__ bias,
                                              float* __restrict__ C,
                                              int M, int N, int K,
                                              int lda, int ldb, int ldc) {
    __shared__ float As[16][64];
    __shared__ float Bs[16][64];
    const int tid = threadIdx.x;
    const int bm = blockIdx.y * 64, bn = blockIdx.x * 64;
    const int ty = tid >> 4, tx = tid & 15;
    float acc[4][4];
#pragma unroll
    for (int i = 0; i < 4; i++)
#pragma unroll
        for (int j = 0; j < 4; j++) acc[i][j] = 0.f;

    const int ar = tid >> 2, ak = (tid & 3) << 2;
    const int bk = tid >> 4, bc2 = (tid & 15) << 2;

    for (int k0 = 0; k0 < K; k0 += 16) {
        float4 a0 = *(const float4*)&A[(size_t)(bm + ar) * lda + k0 + ak];
        float4 b0 = *(const float4*)&B[(size_t)(k0 + bk) * ldb + bn + bc2];
        __syncthreads();
        As[ak + 0][ar] = a0.x; As[ak + 1][ar] = a0.y;
        As[ak + 2][ar] = a0.z; As[ak + 3][ar] = a0.w;
        *(float4*)&Bs[bk][bc2] = b0;
        __syncthreads();
#pragma unroll
        for (int k = 0; k < 16; k++) {
            float a[4], b[4];
            *(float4*)&a[0] = *(const float4*)&As[k][ty * 4];
            *(float4*)&b[0] = *(const float4*)&Bs[k][tx * 4];
#pragma unroll
            for (int i = 0; i < 4; i++)
#pragma unroll
                for (int j = 0; j < 4; j++) acc[i][j] = fmaf(a[i], b[j], acc[i][j]);
        }
    }
#pragma unroll
    for (int i = 0; i < 4; i++) {
        const int row = bm + ty * 4 + i;
        const int col = bn + tx * 4;
        float4 v;
        if (EPI == 2) {
            v = make_float4(softplusf_(acc[i][0] + bias[col + 0]),
                            softplusf_(acc[i][1] + bias[col + 1]),
                            softplusf_(acc[i][2] + bias[col + 2]),
                            softplusf_(acc[i][3] + bias[col + 3]));
        } else {
            v = make_float4(acc[i][0], acc[i][1], acc[i][2], acc[i][3]);
        }
        *(float4*)&C[(size_t)row * ldc + col] = v;
    }
}

// ---------------- conv (k=4, causal) + silu -----------------
__global__ __launch_bounds__(256) void conv_silu(const float* __restrict__ xc,
                                                 const float* __restrict__ cw,
                                                 const float* __restrict__ cb,
                                                 float* __restrict__ xs) {
    const int gid = blockIdx.x * 256 + threadIdx.x;  // l*DI + d
    const int l = gid >> 11;
    const int d = gid & (DI - 1);
    const float4 w = *(const float4*)&cw[d * 4];
    float acc = cb[d];
    const float wj[4] = {w.x, w.y, w.z, w.w};
#pragma unroll
    for (int j = 0; j < 4; j++) {
        const int li = l + j - 3;
        if (li >= 0) acc = fmaf(xc[(size_t)li * DI + d], wj[j], acc);
    }
    xs[gid] = siluf_(acc);
}

// ---------------- GEMM2: xs[L,DI] @ Wx[DI,96] split-K -----------------
__global__ __launch_bounds__(256) void gemm2_splitk(const float* __restrict__ xs,
                                                    const float* __restrict__ Wx,
                                                    float* __restrict__ part) {
    __shared__ float As[32][64];
    __shared__ float Bs[32 * 96];
    const int tid = threadIdx.x;
    const int bm = blockIdx.x * 64;
    const int ks = blockIdx.y;
    const int ty = tid >> 4, tx = tid & 15;
    float acc[4][6];
#pragma unroll
    for (int i = 0; i < 4; i++)
#pragma unroll
        for (int j = 0; j < 6; j++) acc[i][j] = 0.f;

    for (int kt = 0; kt < G2KC; kt += 32) {
        const int kbase = ks * G2KC + kt;
        float4 av[2];
        int arr[2], akk[2];
#pragma unroll
        for (int i = 0; i < 2; i++) {
            const int f = tid + 256 * i;  // 0..511
            arr[i] = f >> 3;
            akk[i] = (f & 7) << 2;
            av[i] = *(const float4*)&xs[(size_t)(bm + arr[i]) * DI + kbase + akk[i]];
        }
        float4 bv[3];
        int bro[3], bco[3];
#pragma unroll
        for (int i = 0; i < 3; i++) {
            const int f = tid + 256 * i;  // float4 index, 0..767
            bro[i] = (f << 2) / 96;
            bco[i] = (f << 2) % 96;
            bv[i] = *(const float4*)&Wx[(size_t)(kbase + bro[i]) * 96 + bco[i]];
        }
        __syncthreads();
#pragma unroll
        for (int i = 0; i < 2; i++) {
            As[akk[i] + 0][arr[i]] = av[i].x;
            As[akk[i] + 1][arr[i]] = av[i].y;
            As[akk[i] + 2][arr[i]] = av[i].z;
            As[akk[i] + 3][arr[i]] = av[i].w;
        }
#pragma unroll
        for (int i = 0; i < 3; i++)
            *(float4*)&Bs[bro[i] * 96 + bco[i]] = bv[i];
        __syncthreads();
#pragma unroll
        for (int k = 0; k < 32; k++) {
            float a[4], b[6];
            *(float4*)&a[0] = *(const float4*)&As[k][ty * 4];
            *(float2*)&b[0] = *(const float2*)&Bs[k * 96 + tx * 6];
            *(float2*)&b[2] = *(const float2*)&Bs[k * 96 + tx * 6 + 2];
            *(float2*)&b[4] = *(const float2*)&Bs[k * 96 + tx * 6 + 4];
#pragma unroll
            for (int i = 0; i < 4; i++)
#pragma unroll
                for (int j = 0; j < 6; j++) acc[i][j] = fmaf(a[i], b[j], acc[i][j]);
        }
    }
#pragma unroll
    for (int i = 0; i < 4; i++) {
        const int row = bm + ty * 4 + i;
#pragma unroll
        for (int j = 0; j < 6; j++) {
            part[((size_t)ks * LL + row) * NXDBL + tx * 6 + j] = acc[i][j];
        }
    }
}

__global__ __launch_bounds__(256) void gemm2_reduce(const float* __restrict__ part,
                                                    float* __restrict__ xdbl) {
    const int gid = blockIdx.x * 256 + threadIdx.x;
    if (gid < LL * NXDBL) {
        float s = 0.f;
#pragma unroll
        for (int ks = 0; ks < KSPLIT; ks++) s += part[(size_t)ks * LL * NXDBL + gid];
        xdbl[gid] = s;
    }
}

// ---------------- scan phase 1: per-chunk composition -----------------
__global__ __launch_bounds__(256) void scan_phase1(const float* __restrict__ dt,
                                                   const float* __restrict__ xs,
                                                   const float* __restrict__ xdbl,
                                                   const float* __restrict__ A_log,
                                                   float* __restrict__ chA,
                                                   float* __restrict__ chB) {
    const int tid = threadIdx.x;
    const int dl = tid >> 4, n = tid & 15;
    const int d = blockIdx.x * 16 + dl;
    const int c = blockIdx.y;
    const float Adn = -__expf(A_log[d * NS + n]);
    float ap = 1.f, bcmp = 0.f;
    const int l0 = c * CHLEN;
#pragma unroll 4
    for (int l = l0; l < l0 + CHLEN; ++l) {
        const float dtv = dt[(size_t)l * DI + d];
        const float xsv = xs[(size_t)l * DI + d];
        const float Bv = xdbl[(size_t)l * NXDBL + DTR + n];
        const float al = __expf(dtv * Adn);
        bcmp = fmaf(al, bcmp, dtv * Bv * xsv);
        ap *= al;
    }
    const size_t o = ((size_t)c * DI + d) * NS + n;
    chA[o] = ap;
    chB[o] = bcmp;
}

// ---------------- scan phase 2: serial prefix over chunks -----------------
__global__ __launch_bounds__(256) void scan_phase2(const float* __restrict__ chA,
                                                   const float* __restrict__ chB,
                                                   float* __restrict__ h0,
                                                   float* __restrict__ hT_out) {
    const int t = blockIdx.x * 256 + threadIdx.x;  // 0..DI*NS-1
    float h = 0.f;
#pragma unroll
    for (int c = 0; c < NCHUNK; ++c) {
        const size_t o = (size_t)c * DI * NS + t;
        h0[o] = h;
        h = fmaf(chA[o], h, chB[o]);
    }
    hT_out[t] = h;
}

// ---------------- scan phase 3: re-scan with h0, fused y epilogue -----------------
__global__ __launch_bounds__(256) void scan_phase3(const float* __restrict__ dt,
                                                   const float* __restrict__ xs,
                                                   const float* __restrict__ xdbl,
                                                   const float* __restrict__ A_log,
                                                   const float* __restrict__ h0,
                                                   const float* __restrict__ Dw,
                                                   const float* __restrict__ res,
                                                   float* __restrict__ y) {
    const int tid = threadIdx.x;
    const int dl = tid >> 4, n = tid & 15;
    const int d = blockIdx.x * 16 + dl;
    const int c = blockIdx.y;
    const float Adn = -__expf(A_log[d * NS + n]);
    float h = h0[((size_t)c * DI + d) * NS + n];
    const float Dd = Dw[d];
    const int l0 = c * CHLEN;
    for (int l = l0; l < l0 + CHLEN; ++l) {
        const float dtv = dt[(size_t)l * DI + d];
        const float xsv = xs[(size_t)l * DI + d];
        const float Bv = xdbl[(size_t)l * NXDBL + DTR + n];
        const float Cv = xdbl[(size_t)l * NXDBL + DTR + NS + n];
        const float al = __expf(dtv * Adn);
        h = fmaf(al, h, dtv * Bv * xsv);
        float p = h * Cv;
        p += __shfl_xor(p, 1);
        p += __shfl_xor(p, 2);
        p += __shfl_xor(p, 4);
        p += __shfl_xor(p, 8);
        if (n == 0) {
            float yv = p + xsv * Dd;
            yv *= siluf_(res[(size_t)l * DI + d]);
            y[(size_t)l * DI + d] = yv;
        }
    }
}

extern "C" void kernel_launch(void* const* d_in, const int* in_sizes, int n_in,
                              void* d_out, int out_size, void* d_ws, size_t ws_size,
                              hipStream_t stream) {
    const float* x = (const float*)d_in[0];
    const float* W_in = (const float*)d_in[1];
    const float* conv_w = (const float*)d_in[2];
    const float* conv_b = (const float*)d_in[3];
    const float* W_x = (const float*)d_in[4];
    const float* W_dt = (const float*)d_in[5];
    const float* b_dt = (const float*)d_in[6];
    const float* A_log = (const float*)d_in[7];
    const float* Dw = (const float*)d_in[8];
    const float* W_out = (const float*)d_in[9];
    float* out = (float*)d_out;

    float* ws = (float*)d_ws;
    float* xc = ws;                              // L*DI  (reused as y later)
    float* res = ws + 4194304;                   // L*DI
    float* xs = ws + 8388608;                    // L*DI
    float* xdbl = ws + 12582912;                 // L*96
    float* dt = ws + 12779520;                   // L*DI
    float* chA = ws + 16973824;                  // C*DI*NS
    float* chB = ws + 18022400;                  // C*DI*NS
    float* h0 = ws + 19070976;                   // C*DI*NS
    float* part = ws + 20119552;                 // 8*L*96
    float* y = xc;

    // 1) x_and_res = x @ W_in  -> xc, res
    gemm128<1><<<dim3(4096 / 128, LL / 128), 256, 0, stream>>>(x, W_in, xc, res,
                                                               LL, 2 * DI, DM);
    // 2) conv + silu -> xs
    conv_silu<<<(LL * DI) / 256, 256, 0, stream>>>(xc, conv_w, conv_b, xs);
    // 3) x_dbl = xs @ W_x (split-K + reduce)
    gemm2_splitk<<<dim3(LL / 64, KSPLIT), 256, 0, stream>>>(xs, W_x, part);
    gemm2_reduce<<<(LL * NXDBL + 255) / 256, 256, 0, stream>>>(part, xdbl);
    // 4) dt = softplus(dt_r @ W_dt + b_dt)
    gemm64<2><<<dim3(DI / 64, LL / 64), 256, 0, stream>>>(xdbl, W_dt, b_dt, dt,
                                                          LL, DI, DTR, NXDBL, DI, DI);
    // 5) chunked scan
    scan_phase1<<<dim3(DI / 16, NCHUNK), 256, 0, stream>>>(dt, xs, xdbl, A_log, chA, chB);
    scan_phase2<<<(DI * NS) / 256, 256, 0, stream>>>(chA, chB, h0, out + (size_t)LL * DM);
    scan_phase3<<<dim3(DI / 16, NCHUNK), 256, 0, stream>>>(dt, xs, xdbl, A_log, h0, Dw,
                                                           res, y);
    // 6) out = y @ W_out
    gemm64<0><<<dim3(DM / 64, LL / 64), 256, 0, stream>>>(y, W_out, nullptr, out,
                                                          LL, DM, DI, DI, DM, DM);
}

// Round 2
// 328.084 us; speedup vs baseline: 1.7015x; 1.7015x over previous
//
#include <hip/hip_runtime.h>
#include <math.h>

#define DM 1024
#define DI 2048
#define NS 16
#define DTR 64
#define LL 2048
#define NXDBL 96      // DTR + 2*NS
#define NCHUNK 32
#define CHLEN 64      // LL / NCHUNK
#define KSPLIT 8
#define G2KC 256      // DI / KSPLIT

typedef unsigned short u16;
typedef __attribute__((ext_vector_type(8))) short short8;
typedef __attribute__((ext_vector_type(4))) float f32x4;

__device__ __forceinline__ float sigmoidf_(float x) { return 1.f / (1.f + __expf(-x)); }
__device__ __forceinline__ float siluf_(float x) { return x * sigmoidf_(x); }
__device__ __forceinline__ float softplusf_(float x) {
    return x > 0.f ? x + log1pf(__expf(-x)) : log1pf(__expf(x));
}
__device__ __forceinline__ u16 f2b(float f) {  // fp32 -> bf16 RNE
    unsigned u = __float_as_uint(f);
    return (u16)((u + 0x7FFFu + ((u >> 16) & 1u)) >> 16);
}

// ---------------- fp32 -> bf16 plain convert (4 elems/thread) -----------------
__global__ __launch_bounds__(256) void convert_plain(const float* __restrict__ src,
                                                     u16* __restrict__ dst) {
    const int i = (blockIdx.x * 256 + threadIdx.x) * 4;
    float4 v = *(const float4*)&src[i];
    u16 o[4] = {f2b(v.x), f2b(v.y), f2b(v.z), f2b(v.w)};
    *(ushort4*)&dst[i] = *(ushort4*)o;
}

// ---------------- fp32 [R][C] -> bf16 [C][R] transpose convert -----------------
__global__ __launch_bounds__(256) void convert_T(const float* __restrict__ src,
                                                 u16* __restrict__ dst, int R, int C) {
    __shared__ float t[32][33];
    const int tx = threadIdx.x & 31, ty = threadIdx.x >> 5;  // ty 0..7
    const int c0 = blockIdx.x * 32, r0 = blockIdx.y * 32;
#pragma unroll
    for (int i = 0; i < 4; i++)
        t[ty + i * 8][tx] = src[(size_t)(r0 + ty + i * 8) * C + c0 + tx];
    __syncthreads();
#pragma unroll
    for (int i = 0; i < 4; i++)
        dst[(size_t)(c0 + ty + i * 8) * R + r0 + tx] = f2b(t[tx][ty + i * 8]);
}

// ---------------- bf16 MFMA GEMM: C[M][N] = A[M][K] @ Bt[N][K]^T -----------------
// 128x128 tile, BK=32, 4 waves (2x2), each wave 64x64 via 4x4 frags of 16x16x32.
// EPI==1: split cols [0,DI)->C0, [DI,2DI)->C1, both ld=DI. EPI==0: plain C0 ld=N.
template <int EPI>
__global__ __launch_bounds__(256) void gemm_mfma(const u16* __restrict__ A,
                                                 const u16* __restrict__ Bt,
                                                 float* __restrict__ C0,
                                                 float* __restrict__ C1,
                                                 int M, int N, int K) {
    __shared__ u16 As[128 * 32];
    __shared__ u16 Bs[128 * 32];
    const int tid = threadIdx.x;
    const int lane = tid & 63;
    const int wave = tid >> 6;
    const int bm = blockIdx.y * 128, bn = blockIdx.x * 128;
    const int wr = wave >> 1, wc = wave & 1;

    f32x4 acc[4][4];
#pragma unroll
    for (int m = 0; m < 4; m++)
#pragma unroll
        for (int n = 0; n < 4; n++) acc[m][n] = (f32x4)0.f;

    // staging: thread tid loads 16B; LDS byte off tid*16 (+4096 for 2nd inst)
    // row = tid/4 (+64), k elem = (tid%4)*8
    const int srow = tid >> 2, skel = (tid & 3) << 3;
    const u16* Ag0 = A + (size_t)(bm + srow) * K + skel;
    const u16* Ag1 = A + (size_t)(bm + 64 + srow) * K + skel;
    const u16* Bg0 = Bt + (size_t)(bn + srow) * K + skel;
    const u16* Bg1 = Bt + (size_t)(bn + 64 + srow) * K + skel;
    u16* Asl = As + tid * 8;
    u16* Bsl = Bs + tid * 8;

    // fragment LDS offsets (ushort units): row-major [128][32]
    const int arow = (wr * 64 + (lane & 15)) * 32 + (lane >> 4) * 8;
    const int brow = (wc * 64 + (lane & 15)) * 32 + (lane >> 4) * 8;

    for (int k0 = 0; k0 < K; k0 += 32) {
        __builtin_amdgcn_global_load_lds(
            (const __attribute__((address_space(1))) unsigned*)(Ag0 + k0),
            (__attribute__((address_space(3))) unsigned*)(Asl), 16, 0, 0);
        __builtin_amdgcn_global_load_lds(
            (const __attribute__((address_space(1))) unsigned*)(Ag1 + k0),
            (__attribute__((address_space(3))) unsigned*)(Asl + 2048), 16, 0, 0);
        __builtin_amdgcn_global_load_lds(
            (const __attribute__((address_space(1))) unsigned*)(Bg0 + k0),
            (__attribute__((address_space(3))) unsigned*)(Bsl), 16, 0, 0);
        __builtin_amdgcn_global_load_lds(
            (const __attribute__((address_space(1))) unsigned*)(Bg1 + k0),
            (__attribute__((address_space(3))) unsigned*)(Bsl + 2048), 16, 0, 0);
        __syncthreads();  // drains vmcnt -> LDS tiles complete, all waves
        short8 av[4], bv[4];
#pragma unroll
        for (int m = 0; m < 4; m++) av[m] = *(const short8*)&As[arow + m * 512];
#pragma unroll
        for (int n = 0; n < 4; n++) bv[n] = *(const short8*)&Bs[brow + n * 512];
#pragma unroll
        for (int m = 0; m < 4; m++)
#pragma unroll
            for (int n = 0; n < 4; n++)
                acc[m][n] = __builtin_amdgcn_mfma_f32_16x16x32_bf16(av[m], bv[n],
                                                                    acc[m][n], 0, 0, 0);
        __syncthreads();  // all reads done before next stage overwrites
    }

    // C/D layout: col = lane&15, row = (lane>>4)*4 + reg   [m89/m91-verified]
    const int crow0 = bm + wr * 64 + (lane >> 4) * 4;
    const int ccol0 = bn + wc * 64 + (lane & 15);
#pragma unroll
    for (int m = 0; m < 4; m++)
#pragma unroll
        for (int n = 0; n < 4; n++) {
            const int col = ccol0 + n * 16;
#pragma unroll
            for (int r = 0; r < 4; r++) {
                const int row = crow0 + m * 16 + r;
                const float v = acc[m][n][r];
                if (EPI == 1) {
                    if (col < DI)
                        C0[(size_t)row * DI + col] = v;
                    else
                        C1[(size_t)row * DI + col - DI] = v;
                } else {
                    C0[(size_t)row * N + col] = v;
                }
            }
        }
}

// ---------------- conv (k=4, causal) + silu -----------------
__global__ __launch_bounds__(256) void conv_silu(const float* __restrict__ xc,
                                                 const float* __restrict__ cw,
                                                 const float* __restrict__ cb,
                                                 float* __restrict__ xs) {
    const int gid = blockIdx.x * 256 + threadIdx.x;  // l*DI + d
    const int l = gid >> 11;
    const int d = gid & (DI - 1);
    const float4 w = *(const float4*)&cw[d * 4];
    float acc = cb[d];
    const float wj[4] = {w.x, w.y, w.z, w.w};
#pragma unroll
    for (int j = 0; j < 4; j++) {
        const int li = l + j - 3;
        if (li >= 0) acc = fmaf(xc[(size_t)li * DI + d], wj[j], acc);
    }
    xs[gid] = siluf_(acc);
}

// ---------------- GEMM2: xs[L,DI] @ Wx[DI,96] split-K -----------------
__global__ __launch_bounds__(256) void gemm2_splitk(const float* __restrict__ xs,
                                                    const float* __restrict__ Wx,
                                                    float* __restrict__ part) {
    __shared__ float As[32][64];
    __shared__ float Bs[32 * 96];
    const int tid = threadIdx.x;
    const int bm = blockIdx.x * 64;
    const int ks = blockIdx.y;
    const int ty = tid >> 4, tx = tid & 15;
    float acc[4][6];
#pragma unroll
    for (int i = 0; i < 4; i++)
#pragma unroll
        for (int j = 0; j < 6; j++) acc[i][j] = 0.f;

    for (int kt = 0; kt < G2KC; kt += 32) {
        const int kbase = ks * G2KC + kt;
        float4 av[2];
        int arr[2], akk[2];
#pragma unroll
        for (int i = 0; i < 2; i++) {
            const int f = tid + 256 * i;
            arr[i] = f >> 3;
            akk[i] = (f & 7) << 2;
            av[i] = *(const float4*)&xs[(size_t)(bm + arr[i]) * DI + kbase + akk[i]];
        }
        float4 bv[3];
        int bro[3], bco[3];
#pragma unroll
        for (int i = 0; i < 3; i++) {
            const int f = tid + 256 * i;
            bro[i] = (f << 2) / 96;
            bco[i] = (f << 2) % 96;
            bv[i] = *(const float4*)&Wx[(size_t)(kbase + bro[i]) * 96 + bco[i]];
        }
        __syncthreads();
#pragma unroll
        for (int i = 0; i < 2; i++) {
            As[akk[i] + 0][arr[i]] = av[i].x;
            As[akk[i] + 1][arr[i]] = av[i].y;
            As[akk[i] + 2][arr[i]] = av[i].z;
            As[akk[i] + 3][arr[i]] = av[i].w;
        }
#pragma unroll
        for (int i = 0; i < 3; i++)
            *(float4*)&Bs[bro[i] * 96 + bco[i]] = bv[i];
        __syncthreads();
#pragma unroll
        for (int k = 0; k < 32; k++) {
            float a[4], b[6];
            *(float4*)&a[0] = *(const float4*)&As[k][ty * 4];
            *(float2*)&b[0] = *(const float2*)&Bs[k * 96 + tx * 6];
            *(float2*)&b[2] = *(const float2*)&Bs[k * 96 + tx * 6 + 2];
            *(float2*)&b[4] = *(const float2*)&Bs[k * 96 + tx * 6 + 4];
#pragma unroll
            for (int i = 0; i < 4; i++)
#pragma unroll
                for (int j = 0; j < 6; j++) acc[i][j] = fmaf(a[i], b[j], acc[i][j]);
        }
    }
#pragma unroll
    for (int i = 0; i < 4; i++) {
        const int row = bm + ty * 4 + i;
#pragma unroll
        for (int j = 0; j < 6; j++) {
            part[((size_t)ks * LL + row) * NXDBL + tx * 6 + j] = acc[i][j];
        }
    }
}

__global__ __launch_bounds__(256) void gemm2_reduce(const float* __restrict__ part,
                                                    float* __restrict__ xdbl) {
    const int gid = blockIdx.x * 256 + threadIdx.x;
    if (gid < LL * NXDBL) {
        float s = 0.f;
#pragma unroll
        for (int ks = 0; ks < KSPLIT; ks++) s += part[(size_t)ks * LL * NXDBL + gid];
        xdbl[gid] = s;
    }
}

// ---------------- GEMM 64x64 tile fp32 (dt path, K=64) -----------------
template <int EPI>
__global__ __launch_bounds__(256) void gemm64(const float* __restrict__ A,
                                              const float* __restrict__ B,
                                              const float* __restrict__ bias,
                                              float* __restrict__ C,
                                              int M, int N, int K,
                                              int lda, int ldb, int ldc) {
    __shared__ float As[16][64];
    __shared__ float Bs[16][64];
    const int tid = threadIdx.x;
    const int bm = blockIdx.y * 64, bn = blockIdx.x * 64;
    const int ty = tid >> 4, tx = tid & 15;
    float acc[4][4];
#pragma unroll
    for (int i = 0; i < 4; i++)
#pragma unroll
        for (int j = 0; j < 4; j++) acc[i][j] = 0.f;

    const int ar = tid >> 2, ak = (tid & 3) << 2;
    const int bk = tid >> 4, bc2 = (tid & 15) << 2;

    for (int k0 = 0; k0 < K; k0 += 16) {
        float4 a0 = *(const float4*)&A[(size_t)(bm + ar) * lda + k0 + ak];
        float4 b0 = *(const float4*)&B[(size_t)(k0 + bk) * ldb + bn + bc2];
        __syncthreads();
        As[ak + 0][ar] = a0.x; As[ak + 1][ar] = a0.y;
        As[ak + 2][ar] = a0.z; As[ak + 3][ar] = a0.w;
        *(float4*)&Bs[bk][bc2] = b0;
        __syncthreads();
#pragma unroll
        for (int k = 0; k < 16; k++) {
            float a[4], b[4];
            *(float4*)&a[0] = *(const float4*)&As[k][ty * 4];
            *(float4*)&b[0] = *(const float4*)&Bs[k][tx * 4];
#pragma unroll
            for (int i = 0; i < 4; i++)
#pragma unroll
                for (int j = 0; j < 4; j++) acc[i][j] = fmaf(a[i], b[j], acc[i][j]);
        }
    }
#pragma unroll
    for (int i = 0; i < 4; i++) {
        const int row = bm + ty * 4 + i;
        const int col = bn + tx * 4;
        float4 v;
        if (EPI == 2) {
            v = make_float4(softplusf_(acc[i][0] + bias[col + 0]),
                            softplusf_(acc[i][1] + bias[col + 1]),
                            softplusf_(acc[i][2] + bias[col + 2]),
                            softplusf_(acc[i][3] + bias[col + 3]));
        } else {
            v = make_float4(acc[i][0], acc[i][1], acc[i][2], acc[i][3]);
        }
        *(float4*)&C[(size_t)row * ldc + col] = v;
    }
}

// ---------------- scan phase 1: per-chunk composition -----------------
__global__ __launch_bounds__(256) void scan_phase1(const float* __restrict__ dt,
                                                   const float* __restrict__ xs,
                                                   const float* __restrict__ xdbl,
                                                   const float* __restrict__ A_log,
                                                   float* __restrict__ chA,
                                                   float* __restrict__ chB) {
    const int tid = threadIdx.x;
    const int dl = tid >> 4, n = tid & 15;
    const int d = blockIdx.x * 16 + dl;
    const int c = blockIdx.y;
    const float Adn = -__expf(A_log[d * NS + n]);
    float ap = 1.f, bcmp = 0.f;
    const int l0 = c * CHLEN;
#pragma unroll 4
    for (int l = l0; l < l0 + CHLEN; ++l) {
        const float dtv = dt[(size_t)l * DI + d];
        const float xsv = xs[(size_t)l * DI + d];
        const float Bv = xdbl[(size_t)l * NXDBL + DTR + n];
        const float al = __expf(dtv * Adn);
        bcmp = fmaf(al, bcmp, dtv * Bv * xsv);
        ap *= al;
    }
    const size_t o = ((size_t)c * DI + d) * NS + n;
    chA[o] = ap;
    chB[o] = bcmp;
}

// ---------------- scan phase 2: serial prefix over chunks -----------------
__global__ __launch_bounds__(256) void scan_phase2(const float* __restrict__ chA,
                                                   const float* __restrict__ chB,
                                                   float* __restrict__ h0,
                                                   float* __restrict__ hT_out) {
    const int t = blockIdx.x * 256 + threadIdx.x;  // 0..DI*NS-1
    float h = 0.f;
#pragma unroll
    for (int c = 0; c < NCHUNK; ++c) {
        const size_t o = (size_t)c * DI * NS + t;
        h0[o] = h;
        h = fmaf(chA[o], h, chB[o]);
    }
    hT_out[t] = h;
}

// ---------------- scan phase 3: re-scan with h0, fused y epilogue (bf16 y) -----------------
__global__ __launch_bounds__(256) void scan_phase3(const float* __restrict__ dt,
                                                   const float* __restrict__ xs,
                                                   const float* __restrict__ xdbl,
                                                   const float* __restrict__ A_log,
                                                   const float* __restrict__ h0,
                                                   const float* __restrict__ Dw,
                                                   const float* __restrict__ res,
                                                   u16* __restrict__ yb) {
    const int tid = threadIdx.x;
    const int dl = tid >> 4, n = tid & 15;
    const int d = blockIdx.x * 16 + dl;
    const int c = blockIdx.y;
    const float Adn = -__expf(A_log[d * NS + n]);
    float h = h0[((size_t)c * DI + d) * NS + n];
    const float Dd = Dw[d];
    const int l0 = c * CHLEN;
    for (int l = l0; l < l0 + CHLEN; ++l) {
        const float dtv = dt[(size_t)l * DI + d];
        const float xsv = xs[(size_t)l * DI + d];
        const float Bv = xdbl[(size_t)l * NXDBL + DTR + n];
        const float Cv = xdbl[(size_t)l * NXDBL + DTR + NS + n];
        const float al = __expf(dtv * Adn);
        h = fmaf(al, h, dtv * Bv * xsv);
        float p = h * Cv;
        p += __shfl_xor(p, 1);
        p += __shfl_xor(p, 2);
        p += __shfl_xor(p, 4);
        p += __shfl_xor(p, 8);
        if (n == 0) {
            float yv = p + xsv * Dd;
            yv *= siluf_(res[(size_t)l * DI + d]);
            yb[(size_t)l * DI + d] = f2b(yv);
        }
    }
}

extern "C" void kernel_launch(void* const* d_in, const int* in_sizes, int n_in,
                              void* d_out, int out_size, void* d_ws, size_t ws_size,
                              hipStream_t stream) {
    const float* x = (const float*)d_in[0];
    const float* W_in = (const float*)d_in[1];
    const float* conv_w = (const float*)d_in[2];
    const float* conv_b = (const float*)d_in[3];
    const float* W_x = (const float*)d_in[4];
    const float* W_dt = (const float*)d_in[5];
    const float* b_dt = (const float*)d_in[6];
    const float* A_log = (const float*)d_in[7];
    const float* Dw = (const float*)d_in[8];
    const float* W_out = (const float*)d_in[9];
    float* out = (float*)d_out;

    float* ws = (float*)d_ws;
    float* xc = ws;                              // L*DI f32
    float* res = ws + 4194304;                   // L*DI f32
    float* xs = ws + 8388608;                    // L*DI f32
    float* xdbl = ws + 12582912;                 // L*96 f32
    float* dt = ws + 12779520;                   // L*DI f32
    float* chA = ws + 16973824;                  // C*DI*NS f32
    float* chB = ws + 18022400;                  // C*DI*NS f32
    float* h0 = ws + 19070976;                   // C*DI*NS f32
    float* part = ws + 20119552;                 // 8*L*96 f32 (6 MB)
    // aliased bf16 buffers (all dead/live windows verified):
    u16* xb = (u16*)part;        // L*DM bf16 (4MB)  — dead before gemm2_splitk writes part
    u16* W_inT_b = (u16*)dt;     // [2DI][DM] bf16 (8MB) — dead before gemm64 writes dt
    u16* W_outT_b = (u16*)chA;   // [DM][DI] bf16 (4MB) — written after scan_phase2 frees chA
    u16* yb = (u16*)xc;          // [L][DI] bf16 (8MB) — xc dead after conv_silu

    // 1) bf16 converts for GEMM1
    convert_plain<<<(LL * DM) / 1024, 256, 0, stream>>>(x, xb);
    convert_T<<<dim3(2 * DI / 32, DM / 32), 256, 0, stream>>>(W_in, W_inT_b, DM, 2 * DI);
    // 2) x_and_res = x @ W_in  (bf16 MFMA) -> xc, res
    gemm_mfma<1><<<dim3(2 * DI / 128, LL / 128), 256, 0, stream>>>(xb, W_inT_b, xc, res,
                                                                   LL, 2 * DI, DM);
    // 3) conv + silu -> xs
    conv_silu<<<(LL * DI) / 256, 256, 0, stream>>>(xc, conv_w, conv_b, xs);
    // 4) x_dbl = xs @ W_x (split-K + reduce)
    gemm2_splitk<<<dim3(LL / 64, KSPLIT), 256, 0, stream>>>(xs, W_x, part);
    gemm2_reduce<<<(LL * NXDBL + 255) / 256, 256, 0, stream>>>(part, xdbl);
    // 5) dt = softplus(dt_r @ W_dt + b_dt)
    gemm64<2><<<dim3(DI / 64, LL / 64), 256, 0, stream>>>(xdbl, W_dt, b_dt, dt,
                                                          LL, DI, DTR, NXDBL, DI, DI);
    // 6) chunked scan
    scan_phase1<<<dim3(DI / 16, NCHUNK), 256, 0, stream>>>(dt, xs, xdbl, A_log, chA, chB);
    scan_phase2<<<(DI * NS) / 256, 256, 0, stream>>>(chA, chB, h0, out + (size_t)LL * DM);
    // 7) W_out convert (chA now dead) + scan phase 3 -> yb (bf16)
    convert_T<<<dim3(DM / 32, DI / 32), 256, 0, stream>>>(W_out, W_outT_b, DI, DM);
    scan_phase3<<<dim3(DI / 16, NCHUNK), 256, 0, stream>>>(dt, xs, xdbl, A_log, h0, Dw,
                                                           res, yb);
    // 8) out = y @ W_out (bf16 MFMA)
    gemm_mfma<0><<<dim3(DM / 128, LL / 128), 256, 0, stream>>>(yb, W_outT_b, out, nullptr,
                                                               LL, DM, DI);
}

// Round 3
// 248.675 us; speedup vs baseline: 2.2448x; 1.3193x over previous
//
#include <hip/hip_runtime.h>
#include <math.h>

#define DM 1024
#define DI 2048
#define NS 16
#define DTR 64
#define LL 2048
#define NXDBL 96      // DTR + 2*NS
#define NCHUNK 64
#define CHLEN 32      // LL / NCHUNK
#define KSPLIT 8
#define G2KC 256      // DI / KSPLIT

typedef unsigned short u16;
typedef __attribute__((ext_vector_type(8))) short short8;
typedef __attribute__((ext_vector_type(4))) float f32x4;

__device__ __forceinline__ float sigmoidf_(float x) { return 1.f / (1.f + __expf(-x)); }
__device__ __forceinline__ float siluf_(float x) { return x * sigmoidf_(x); }
__device__ __forceinline__ float softplusf_(float x) {
    return x > 0.f ? x + log1pf(__expf(-x)) : log1pf(__expf(x));
}
__device__ __forceinline__ u16 f2b(float f) {  // fp32 -> bf16 RNE
    unsigned u = __float_as_uint(f);
    return (u16)((u + 0x7FFFu + ((u >> 16) & 1u)) >> 16);
}

// ---------------- fp32 -> bf16 plain convert (4 elems/thread) -----------------
__global__ __launch_bounds__(256) void convert_plain(const float* __restrict__ src,
                                                     u16* __restrict__ dst) {
    const int i = (blockIdx.x * 256 + threadIdx.x) * 4;
    float4 v = *(const float4*)&src[i];
    u16 o[4] = {f2b(v.x), f2b(v.y), f2b(v.z), f2b(v.w)};
    *(ushort4*)&dst[i] = *(ushort4*)o;
}

// ---------------- fp32 [R][C] -> bf16 [C][R] transpose convert -----------------
__global__ __launch_bounds__(256) void convert_T(const float* __restrict__ src,
                                                 u16* __restrict__ dst, int R, int C) {
    __shared__ float t[32][33];
    const int tx = threadIdx.x & 31, ty = threadIdx.x >> 5;  // ty 0..7
    const int c0 = blockIdx.x * 32, r0 = blockIdx.y * 32;
#pragma unroll
    for (int i = 0; i < 4; i++)
        t[ty + i * 8][tx] = src[(size_t)(r0 + ty + i * 8) * C + c0 + tx];
    __syncthreads();
#pragma unroll
    for (int i = 0; i < 4; i++)
        dst[(size_t)(c0 + ty + i * 8) * R + r0 + tx] = f2b(t[tx][ty + i * 8]);
}

// ---------------- bf16 MFMA GEMM: C[M][N] = A[M][K] @ Bt[N][K]^T -----------------
template <int EPI>
__global__ __launch_bounds__(256) void gemm_mfma(const u16* __restrict__ A,
                                                 const u16* __restrict__ Bt,
                                                 float* __restrict__ C0,
                                                 float* __restrict__ C1,
                                                 int M, int N, int K) {
    __shared__ u16 As[128 * 32];
    __shared__ u16 Bs[128 * 32];
    const int tid = threadIdx.x;
    const int lane = tid & 63;
    const int wave = tid >> 6;
    const int bm = blockIdx.y * 128, bn = blockIdx.x * 128;
    const int wr = wave >> 1, wc = wave & 1;

    f32x4 acc[4][4];
#pragma unroll
    for (int m = 0; m < 4; m++)
#pragma unroll
        for (int n = 0; n < 4; n++) acc[m][n] = (f32x4)0.f;

    const int srow = tid >> 2, skel = (tid & 3) << 3;
    const u16* Ag0 = A + (size_t)(bm + srow) * K + skel;
    const u16* Ag1 = A + (size_t)(bm + 64 + srow) * K + skel;
    const u16* Bg0 = Bt + (size_t)(bn + srow) * K + skel;
    const u16* Bg1 = Bt + (size_t)(bn + 64 + srow) * K + skel;
    u16* Asl = As + tid * 8;
    u16* Bsl = Bs + tid * 8;

    const int arow = (wr * 64 + (lane & 15)) * 32 + (lane >> 4) * 8;
    const int brow = (wc * 64 + (lane & 15)) * 32 + (lane >> 4) * 8;

    for (int k0 = 0; k0 < K; k0 += 32) {
        __builtin_amdgcn_global_load_lds(
            (const __attribute__((address_space(1))) unsigned*)(Ag0 + k0),
            (__attribute__((address_space(3))) unsigned*)(Asl), 16, 0, 0);
        __builtin_amdgcn_global_load_lds(
            (const __attribute__((address_space(1))) unsigned*)(Ag1 + k0),
            (__attribute__((address_space(3))) unsigned*)(Asl + 2048), 16, 0, 0);
        __builtin_amdgcn_global_load_lds(
            (const __attribute__((address_space(1))) unsigned*)(Bg0 + k0),
            (__attribute__((address_space(3))) unsigned*)(Bsl), 16, 0, 0);
        __builtin_amdgcn_global_load_lds(
            (const __attribute__((address_space(1))) unsigned*)(Bg1 + k0),
            (__attribute__((address_space(3))) unsigned*)(Bsl + 2048), 16, 0, 0);
        __syncthreads();
        short8 av[4], bv[4];
#pragma unroll
        for (int m = 0; m < 4; m++) av[m] = *(const short8*)&As[arow + m * 512];
#pragma unroll
        for (int n = 0; n < 4; n++) bv[n] = *(const short8*)&Bs[brow + n * 512];
#pragma unroll
        for (int m = 0; m < 4; m++)
#pragma unroll
            for (int n = 0; n < 4; n++)
                acc[m][n] = __builtin_amdgcn_mfma_f32_16x16x32_bf16(av[m], bv[n],
                                                                    acc[m][n], 0, 0, 0);
        __syncthreads();
    }

    const int crow0 = bm + wr * 64 + (lane >> 4) * 4;
    const int ccol0 = bn + wc * 64 + (lane & 15);
#pragma unroll
    for (int m = 0; m < 4; m++)
#pragma unroll
        for (int n = 0; n < 4; n++) {
            const int col = ccol0 + n * 16;
#pragma unroll
            for (int r = 0; r < 4; r++) {
                const int row = crow0 + m * 16 + r;
                const float v = acc[m][n][r];
                if (EPI == 1) {
                    if (col < DI)
                        C0[(size_t)row * DI + col] = v;
                    else
                        C1[(size_t)row * DI + col - DI] = v;
                } else {
                    C0[(size_t)row * N + col] = v;
                }
            }
        }
}

// ---------------- conv (k=4, causal) + silu -----------------
__global__ __launch_bounds__(256) void conv_silu(const float* __restrict__ xc,
                                                 const float* __restrict__ cw,
                                                 const float* __restrict__ cb,
                                                 float* __restrict__ xs) {
    const int gid = blockIdx.x * 256 + threadIdx.x;  // l*DI + d
    const int l = gid >> 11;
    const int d = gid & (DI - 1);
    const float4 w = *(const float4*)&cw[d * 4];
    float acc = cb[d];
    const float wj[4] = {w.x, w.y, w.z, w.w};
#pragma unroll
    for (int j = 0; j < 4; j++) {
        const int li = l + j - 3;
        if (li >= 0) acc = fmaf(xc[(size_t)li * DI + d], wj[j], acc);
    }
    xs[gid] = siluf_(acc);
}

// ---------------- GEMM2: xs[L,DI] @ Wx[DI,96] split-K -----------------
__global__ __launch_bounds__(256) void gemm2_splitk(const float* __restrict__ xs,
                                                    const float* __restrict__ Wx,
                                                    float* __restrict__ part) {
    __shared__ float As[32][64];
    __shared__ float Bs[32 * 96];
    const int tid = threadIdx.x;
    const int bm = blockIdx.x * 64;
    const int ks = blockIdx.y;
    const int ty = tid >> 4, tx = tid & 15;
    float acc[4][6];
#pragma unroll
    for (int i = 0; i < 4; i++)
#pragma unroll
        for (int j = 0; j < 6; j++) acc[i][j] = 0.f;

    for (int kt = 0; kt < G2KC; kt += 32) {
        const int kbase = ks * G2KC + kt;
        float4 av[2];
        int arr[2], akk[2];
#pragma unroll
        for (int i = 0; i < 2; i++) {
            const int f = tid + 256 * i;
            arr[i] = f >> 3;
            akk[i] = (f & 7) << 2;
            av[i] = *(const float4*)&xs[(size_t)(bm + arr[i]) * DI + kbase + akk[i]];
        }
        float4 bv[3];
        int bro[3], bco[3];
#pragma unroll
        for (int i = 0; i < 3; i++) {
            const int f = tid + 256 * i;
            bro[i] = (f << 2) / 96;
            bco[i] = (f << 2) % 96;
            bv[i] = *(const float4*)&Wx[(size_t)(kbase + bro[i]) * 96 + bco[i]];
        }
        __syncthreads();
#pragma unroll
        for (int i = 0; i < 2; i++) {
            As[akk[i] + 0][arr[i]] = av[i].x;
            As[akk[i] + 1][arr[i]] = av[i].y;
            As[akk[i] + 2][arr[i]] = av[i].z;
            As[akk[i] + 3][arr[i]] = av[i].w;
        }
#pragma unroll
        for (int i = 0; i < 3; i++)
            *(float4*)&Bs[bro[i] * 96 + bco[i]] = bv[i];
        __syncthreads();
#pragma unroll
        for (int k = 0; k < 32; k++) {
            float a[4], b[6];
            *(float4*)&a[0] = *(const float4*)&As[k][ty * 4];
            *(float2*)&b[0] = *(const float2*)&Bs[k * 96 + tx * 6];
            *(float2*)&b[2] = *(const float2*)&Bs[k * 96 + tx * 6 + 2];
            *(float2*)&b[4] = *(const float2*)&Bs[k * 96 + tx * 6 + 4];
#pragma unroll
            for (int i = 0; i < 4; i++)
#pragma unroll
                for (int j = 0; j < 6; j++) acc[i][j] = fmaf(a[i], b[j], acc[i][j]);
        }
    }
#pragma unroll
    for (int i = 0; i < 4; i++) {
        const int row = bm + ty * 4 + i;
#pragma unroll
        for (int j = 0; j < 6; j++) {
            part[((size_t)ks * LL + row) * NXDBL + tx * 6 + j] = acc[i][j];
        }
    }
}

__global__ __launch_bounds__(256) void gemm2_reduce(const float* __restrict__ part,
                                                    float* __restrict__ xdbl) {
    const int gid = blockIdx.x * 256 + threadIdx.x;
    if (gid < LL * NXDBL) {
        float s = 0.f;
#pragma unroll
        for (int ks = 0; ks < KSPLIT; ks++) s += part[(size_t)ks * LL * NXDBL + gid];
        xdbl[gid] = s;
    }
}

// ---------------- GEMM 64x64 tile fp32 (dt path, K=64) -----------------
template <int EPI>
__global__ __launch_bounds__(256) void gemm64(const float* __restrict__ A,
                                              const float* __restrict__ B,
                                              const float* __restrict__ bias,
                                              float* __restrict__ C,
                                              int M, int N, int K,
                                              int lda, int ldb, int ldc) {
    __shared__ float As[16][64];
    __shared__ float Bs[16][64];
    const int tid = threadIdx.x;
    const int bm = blockIdx.y * 64, bn = blockIdx.x * 64;
    const int ty = tid >> 4, tx = tid & 15;
    float acc[4][4];
#pragma unroll
    for (int i = 0; i < 4; i++)
#pragma unroll
        for (int j = 0; j < 4; j++) acc[i][j] = 0.f;

    const int ar = tid >> 2, ak = (tid & 3) << 2;
    const int bk = tid >> 4, bc2 = (tid & 15) << 2;

    for (int k0 = 0; k0 < K; k0 += 16) {
        float4 a0 = *(const float4*)&A[(size_t)(bm + ar) * lda + k0 + ak];
        float4 b0 = *(const float4*)&B[(size_t)(k0 + bk) * ldb + bn + bc2];
        __syncthreads();
        As[ak + 0][ar] = a0.x; As[ak + 1][ar] = a0.y;
        As[ak + 2][ar] = a0.z; As[ak + 3][ar] = a0.w;
        *(float4*)&Bs[bk][bc2] = b0;
        __syncthreads();
#pragma unroll
        for (int k = 0; k < 16; k++) {
            float a[4], b[4];
            *(float4*)&a[0] = *(const float4*)&As[k][ty * 4];
            *(float4*)&b[0] = *(const float4*)&Bs[k][tx * 4];
#pragma unroll
            for (int i = 0; i < 4; i++)
#pragma unroll
                for (int j = 0; j < 4; j++) acc[i][j] = fmaf(a[i], b[j], acc[i][j]);
        }
    }
#pragma unroll
    for (int i = 0; i < 4; i++) {
        const int row = bm + ty * 4 + i;
        const int col = bn + tx * 4;
        float4 v;
        if (EPI == 2) {
            v = make_float4(softplusf_(acc[i][0] + bias[col + 0]),
                            softplusf_(acc[i][1] + bias[col + 1]),
                            softplusf_(acc[i][2] + bias[col + 2]),
                            softplusf_(acc[i][3] + bias[col + 3]));
        } else {
            v = make_float4(acc[i][0], acc[i][1], acc[i][2], acc[i][3]);
        }
        *(float4*)&C[(size_t)row * ldc + col] = v;
    }
}

// ---------------- scan phase 1: per-chunk composition, 16 states/thread ---------
__global__ __launch_bounds__(256) void scan_phase1(const float* __restrict__ dt,
                                                   const float* __restrict__ xs,
                                                   const float* __restrict__ xdbl,
                                                   const float* __restrict__ A_log,
                                                   float* __restrict__ chA,
                                                   float* __restrict__ chB) {
    const int g = blockIdx.x * 256 + threadIdx.x;
    const int d = g & (DI - 1);
    const int c = g >> 11;
    float An2[NS], ap[NS], bc[NS];
    {
        float al[NS];
#pragma unroll
        for (int q = 0; q < 4; q++)
            *(float4*)&al[q * 4] = *(const float4*)&A_log[d * NS + q * 4];
#pragma unroll
        for (int n = 0; n < NS; n++) {
            An2[n] = -__expf(al[n]) * 1.44269504f;
            ap[n] = 1.f;
            bc[n] = 0.f;
        }
    }
    const int l0 = c * CHLEN;
    for (int l = l0; l < l0 + CHLEN; ++l) {
        const float dtv = dt[(size_t)l * DI + d];
        const float xsv = xs[(size_t)l * DI + d];
        const float dx = dtv * xsv;
        float bv[NS];
#pragma unroll
        for (int q = 0; q < 4; q++)
            *(float4*)&bv[q * 4] = *(const float4*)&xdbl[(size_t)l * NXDBL + DTR + q * 4];
#pragma unroll
        for (int n = 0; n < NS; n++) {
            const float al = __builtin_amdgcn_exp2f(dtv * An2[n]);
            ap[n] *= al;
            bc[n] = fmaf(al, bc[n], dx * bv[n]);
        }
    }
    const size_t o = ((size_t)c * DI + d) * NS;
#pragma unroll
    for (int q = 0; q < 4; q++) {
        *(float4*)&chA[o + q * 4] = *(float4*)&ap[q * 4];
        *(float4*)&chB[o + q * 4] = *(float4*)&bc[q * 4];
    }
}

// ---------------- scan phase 2: serial prefix over chunks (h0 in-place in chA) ---
__global__ __launch_bounds__(256) void scan_phase2(float* __restrict__ chA,
                                                   const float* __restrict__ chB,
                                                   float* __restrict__ hT_out) {
    const int t = blockIdx.x * 256 + threadIdx.x;  // 0..DI*NS-1
    float h = 0.f;
#pragma unroll 4
    for (int c = 0; c < NCHUNK; ++c) {
        const size_t o = (size_t)c * DI * NS + t;
        const float a = chA[o];
        const float b = chB[o];
        chA[o] = h;  // h0 for chunk c, overwrites a (already consumed)
        h = fmaf(a, h, b);
    }
    hT_out[t] = h;
}

// ---------------- scan phase 3: re-scan with h0, fused y epilogue (bf16 y) -------
__global__ __launch_bounds__(256) void scan_phase3(const float* __restrict__ dt,
                                                   const float* __restrict__ xs,
                                                   const float* __restrict__ xdbl,
                                                   const float* __restrict__ A_log,
                                                   const float* __restrict__ h0,
                                                   const float* __restrict__ Dw,
                                                   const float* __restrict__ res,
                                                   u16* __restrict__ yb) {
    const int g = blockIdx.x * 256 + threadIdx.x;
    const int d = g & (DI - 1);
    const int c = g >> 11;
    float An2[NS], h[NS];
    {
        float al[NS];
#pragma unroll
        for (int q = 0; q < 4; q++)
            *(float4*)&al[q * 4] = *(const float4*)&A_log[d * NS + q * 4];
#pragma unroll
        for (int n = 0; n < NS; n++) An2[n] = -__expf(al[n]) * 1.44269504f;
    }
    const size_t ho = ((size_t)c * DI + d) * NS;
#pragma unroll
    for (int q = 0; q < 4; q++) *(float4*)&h[q * 4] = *(const float4*)&h0[ho + q * 4];
    const float Dd = Dw[d];
    const int l0 = c * CHLEN;
    for (int l = l0; l < l0 + CHLEN; ++l) {
        const float dtv = dt[(size_t)l * DI + d];
        const float xsv = xs[(size_t)l * DI + d];
        const float resv = res[(size_t)l * DI + d];
        const float dx = dtv * xsv;
        float bv[NS], cv[NS];
#pragma unroll
        for (int q = 0; q < 4; q++) {
            *(float4*)&bv[q * 4] = *(const float4*)&xdbl[(size_t)l * NXDBL + DTR + q * 4];
            *(float4*)&cv[q * 4] =
                *(const float4*)&xdbl[(size_t)l * NXDBL + DTR + NS + q * 4];
        }
#pragma unroll
        for (int n = 0; n < NS; n++) {
            const float al = __builtin_amdgcn_exp2f(dtv * An2[n]);
            h[n] = fmaf(al, h[n], dx * bv[n]);
        }
        float y0 = 0.f, y1 = 0.f, y2 = 0.f, y3 = 0.f;
#pragma unroll
        for (int n = 0; n < NS; n += 4) {
            y0 = fmaf(h[n + 0], cv[n + 0], y0);
            y1 = fmaf(h[n + 1], cv[n + 1], y1);
            y2 = fmaf(h[n + 2], cv[n + 2], y2);
            y3 = fmaf(h[n + 3], cv[n + 3], y3);
        }
        float yv = ((y0 + y1) + (y2 + y3)) + xsv * Dd;
        yv *= siluf_(resv);
        yb[(size_t)l * DI + d] = f2b(yv);
    }
}

extern "C" void kernel_launch(void* const* d_in, const int* in_sizes, int n_in,
                              void* d_out, int out_size, void* d_ws, size_t ws_size,
                              hipStream_t stream) {
    const float* x = (const float*)d_in[0];
    const float* W_in = (const float*)d_in[1];
    const float* conv_w = (const float*)d_in[2];
    const float* conv_b = (const float*)d_in[3];
    const float* W_x = (const float*)d_in[4];
    const float* W_dt = (const float*)d_in[5];
    const float* b_dt = (const float*)d_in[6];
    const float* A_log = (const float*)d_in[7];
    const float* Dw = (const float*)d_in[8];
    const float* W_out = (const float*)d_in[9];
    float* out = (float*)d_out;

    float* ws = (float*)d_ws;
    float* xc = ws;                    // [0, 4194304)        L*DI f32 ; later yb (bf16)
    float* res = ws + 4194304;         // [4194304, 8388608)  L*DI f32
    float* xs = ws + 8388608;          // [8388608, 12582912) L*DI f32
    float* dt = ws + 12582912;         // [12582912,16777216) L*DI f32 ; earlier W_inT_b
    float* xdbl = ws + 16777216;       // [16777216,16973824) L*96 f32
    float* chA = ws + 16973824;        // [16973824,19070976) NCHUNK*DI*NS f32 (->h0)
    float* chB = ws + 19070976;        // [19070976,21168128) NCHUNK*DI*NS f32
                                       //   also hosts: xb, part, W_outT_b (disjoint)
    // aliased buffers:
    u16* xb = (u16*)chB;          // L*DM bf16 (2M u16) — live convert->gemm1
    float* part = chB;            // 8*L*96 f32 (1.57M) — live gemm2_splitk->reduce
    u16* W_outT_b = (u16*)chB;    // DM*DI bf16 (1M u16-eq) — live after phase2
    u16* W_inT_b = (u16*)dt;      // 2DI*DM bf16 (2M float-eq) — dead before dt written
    u16* yb = (u16*)xc;           // L*DI bf16 — xc dead after conv_silu

    // 1) bf16 converts for GEMM1
    convert_plain<<<(LL * DM) / 1024, 256, 0, stream>>>(x, xb);
    convert_T<<<dim3(2 * DI / 32, DM / 32), 256, 0, stream>>>(W_in, W_inT_b, DM, 2 * DI);
    // 2) x_and_res = x @ W_in  (bf16 MFMA) -> xc, res
    gemm_mfma<1><<<dim3(2 * DI / 128, LL / 128), 256, 0, stream>>>(xb, W_inT_b, xc, res,
                                                                   LL, 2 * DI, DM);
    // 3) conv + silu -> xs
    conv_silu<<<(LL * DI) / 256, 256, 0, stream>>>(xc, conv_w, conv_b, xs);
    // 4) x_dbl = xs @ W_x (split-K + reduce)  (part overwrites xb — dead)
    gemm2_splitk<<<dim3(LL / 64, KSPLIT), 256, 0, stream>>>(xs, W_x, part);
    gemm2_reduce<<<(LL * NXDBL + 255) / 256, 256, 0, stream>>>(part, xdbl);
    // 5) dt = softplus(dt_r @ W_dt + b_dt)  (overwrites W_inT_b — dead)
    gemm64<2><<<dim3(DI / 64, LL / 64), 256, 0, stream>>>(xdbl, W_dt, b_dt, dt,
                                                          LL, DI, DTR, NXDBL, DI, DI);
    // 6) chunked scan (chB overwrites part — dead)
    scan_phase1<<<(DI * NCHUNK) / 256, 256, 0, stream>>>(dt, xs, xdbl, A_log, chA, chB);
    scan_phase2<<<(DI * NS) / 256, 256, 0, stream>>>(chA, chB, out + (size_t)LL * DM);
    // 7) W_out convert (chB dead after phase2) + scan phase 3 -> yb (bf16)
    convert_T<<<dim3(DM / 32, DI / 32), 256, 0, stream>>>(W_out, W_outT_b, DI, DM);
    scan_phase3<<<(DI * NCHUNK) / 256, 256, 0, stream>>>(dt, xs, xdbl, A_log, chA, Dw,
                                                         res, yb);
    // 8) out = y @ W_out (bf16 MFMA)
    gemm_mfma<0><<<dim3(DM / 128, LL / 128), 256, 0, stream>>>(yb, W_outT_b, out, nullptr,
                                                               LL, DM, DI);
}

// Round 4
// 237.461 us; speedup vs baseline: 2.3508x; 1.0472x over previous
//
#include <hip/hip_runtime.h>
#include <math.h>

#define DM 1024
#define DI 2048
#define NS 16
#define DTR 64
#define LL 2048
#define NXDBL 96      // DTR + 2*NS
#define NCHUNK 64
#define CHLEN 32      // LL / NCHUNK
#define KSPLIT 8
#define G2KC 256      // DI / KSPLIT

typedef unsigned short u16;
typedef __attribute__((ext_vector_type(8))) short short8;
typedef __attribute__((ext_vector_type(4))) float f32x4;

__device__ __forceinline__ float sigmoidf_(float x) { return 1.f / (1.f + __expf(-x)); }
__device__ __forceinline__ float siluf_(float x) { return x * sigmoidf_(x); }
__device__ __forceinline__ float softplusf_(float x) {
    return x > 0.f ? x + log1pf(__expf(-x)) : log1pf(__expf(x));
}
__device__ __forceinline__ u16 f2b(float f) {  // fp32 -> bf16 RNE
    unsigned u = __float_as_uint(f);
    return (u16)((u + 0x7FFFu + ((u >> 16) & 1u)) >> 16);
}

// ---------------- fp32 -> bf16 plain convert (4 elems/thread) -----------------
__global__ __launch_bounds__(256) void convert_plain(const float* __restrict__ src,
                                                     u16* __restrict__ dst) {
    const int i = (blockIdx.x * 256 + threadIdx.x) * 4;
    float4 v = *(const float4*)&src[i];
    u16 o[4] = {f2b(v.x), f2b(v.y), f2b(v.z), f2b(v.w)};
    *(ushort4*)&dst[i] = *(ushort4*)o;
}

// ---------------- fp32 [R][C] -> bf16 [C][R] transpose convert -----------------
__global__ __launch_bounds__(256) void convert_T(const float* __restrict__ src,
                                                 u16* __restrict__ dst, int R, int C) {
    __shared__ float t[32][33];
    const int tx = threadIdx.x & 31, ty = threadIdx.x >> 5;  // ty 0..7
    const int c0 = blockIdx.x * 32, r0 = blockIdx.y * 32;
#pragma unroll
    for (int i = 0; i < 4; i++)
        t[ty + i * 8][tx] = src[(size_t)(r0 + ty + i * 8) * C + c0 + tx];
    __syncthreads();
#pragma unroll
    for (int i = 0; i < 4; i++)
        dst[(size_t)(c0 + ty + i * 8) * R + r0 + tx] = f2b(t[tx][ty + i * 8]);
}

// ---------------- bf16 MFMA GEMM: C[M][N] = A[M][K] @ Bt[N][K]^T -----------------
// 128x128 tile, BK=32, double-buffered LDS, ONE barrier per K-step (2-phase).
// gridDim.z = split-K factor: block z covers k in [z*k_len, (z+1)*k_len),
// EPI==0 writes fp32 partial to C0 + z*M*N. EPI==1 (gridDim.z==1): split cols
// [0,DI)->C0, [DI,2DI)->C1, both ld=DI.
template <int EPI>
__global__ __launch_bounds__(256) void gemm_mfma(const u16* __restrict__ A,
                                                 const u16* __restrict__ Bt,
                                                 float* __restrict__ C0,
                                                 float* __restrict__ C1,
                                                 int M, int N, int lda, int k_len) {
    __shared__ u16 As[2][128 * 32];
    __shared__ u16 Bs[2][128 * 32];
    const int tid = threadIdx.x;
    const int lane = tid & 63;
    const int wave = tid >> 6;
    const int bm = blockIdx.y * 128, bn = blockIdx.x * 128;
    const int wr = wave >> 1, wc = wave & 1;
    const int k_off = blockIdx.z * k_len;

    f32x4 acc[4][4];
#pragma unroll
    for (int m = 0; m < 4; m++)
#pragma unroll
        for (int n = 0; n < 4; n++) acc[m][n] = (f32x4)0.f;

    const int srow = tid >> 2, skel = (tid & 3) << 3;
    const u16* Ag0 = A + (size_t)(bm + srow) * lda + k_off + skel;
    const u16* Ag1 = A + (size_t)(bm + 64 + srow) * lda + k_off + skel;
    const u16* Bg0 = Bt + (size_t)(bn + srow) * lda + k_off + skel;
    const u16* Bg1 = Bt + (size_t)(bn + 64 + srow) * lda + k_off + skel;
    u16* Asl = &As[0][0] + tid * 8;
    u16* Bsl = &Bs[0][0] + tid * 8;

    const int arow = (wr * 64 + (lane & 15)) * 32 + (lane >> 4) * 8;
    const int brow = (wc * 64 + (lane & 15)) * 32 + (lane >> 4) * 8;

#define STAGE(buf, ks)                                                              \
    do {                                                                            \
        __builtin_amdgcn_global_load_lds(                                           \
            (const __attribute__((address_space(1))) unsigned*)(Ag0 + (ks)),        \
            (__attribute__((address_space(3))) unsigned*)(Asl + (buf) * 4096),      \
            16, 0, 0);                                                              \
        __builtin_amdgcn_global_load_lds(                                           \
            (const __attribute__((address_space(1))) unsigned*)(Ag1 + (ks)),        \
            (__attribute__((address_space(3))) unsigned*)(Asl + (buf) * 4096 + 2048),\
            16, 0, 0);                                                              \
        __builtin_amdgcn_global_load_lds(                                           \
            (const __attribute__((address_space(1))) unsigned*)(Bg0 + (ks)),        \
            (__attribute__((address_space(3))) unsigned*)(Bsl + (buf) * 4096),      \
            16, 0, 0);                                                              \
        __builtin_amdgcn_global_load_lds(                                           \
            (const __attribute__((address_space(1))) unsigned*)(Bg1 + (ks)),        \
            (__attribute__((address_space(3))) unsigned*)(Bsl + (buf) * 4096 + 2048),\
            16, 0, 0);                                                              \
    } while (0)

#define COMPUTE(buf)                                                                \
    do {                                                                            \
        short8 av[4], bv[4];                                                        \
        _Pragma("unroll") for (int m = 0; m < 4; m++)                               \
            av[m] = *(const short8*)&As[buf][arow + m * 512];                       \
        _Pragma("unroll") for (int n = 0; n < 4; n++)                               \
            bv[n] = *(const short8*)&Bs[buf][brow + n * 512];                       \
        _Pragma("unroll") for (int m = 0; m < 4; m++)                               \
            _Pragma("unroll") for (int n = 0; n < 4; n++)                           \
                acc[m][n] = __builtin_amdgcn_mfma_f32_16x16x32_bf16(av[m], bv[n],   \
                                                                    acc[m][n], 0, 0, 0); \
    } while (0)

    const int nsteps = k_len >> 5;
    STAGE(0, 0);
    __syncthreads();
    for (int s = 1; s < nsteps; ++s) {
        STAGE(s & 1, s * 32);        // issue next-tile loads (hidden under compute)
        COMPUTE((s - 1) & 1);
        __syncthreads();             // drains vmcnt(0): next buffer ready
    }
    COMPUTE((nsteps - 1) & 1);
#undef STAGE
#undef COMPUTE

    const int crow0 = bm + wr * 64 + (lane >> 4) * 4;
    const int ccol0 = bn + wc * 64 + (lane & 15);
    float* C0z = C0 + (size_t)blockIdx.z * M * N;
#pragma unroll
    for (int m = 0; m < 4; m++)
#pragma unroll
        for (int n = 0; n < 4; n++) {
            const int col = ccol0 + n * 16;
#pragma unroll
            for (int r = 0; r < 4; r++) {
                const int row = crow0 + m * 16 + r;
                const float v = acc[m][n][r];
                if (EPI == 1) {
                    if (col < DI)
                        C0[(size_t)row * DI + col] = v;
                    else
                        C1[(size_t)row * DI + col - DI] = v;
                } else {
                    C0z[(size_t)row * N + col] = v;
                }
            }
        }
}

// ---------------- sum of 2 split-K partials -----------------
__global__ __launch_bounds__(256) void sum2(const float* __restrict__ p,
                                            float* __restrict__ out, int n) {
    const int i = (blockIdx.x * 256 + threadIdx.x) * 4;
    float4 a = *(const float4*)&p[i];
    float4 b = *(const float4*)&p[(size_t)n + i];
    float4 o = make_float4(a.x + b.x, a.y + b.y, a.z + b.z, a.w + b.w);
    *(float4*)&out[i] = o;
}

// ---------------- conv (k=4, causal) + silu -----------------
__global__ __launch_bounds__(256) void conv_silu(const float* __restrict__ xc,
                                                 const float* __restrict__ cw,
                                                 const float* __restrict__ cb,
                                                 float* __restrict__ xs) {
    const int gid = blockIdx.x * 256 + threadIdx.x;  // l*DI + d
    const int l = gid >> 11;
    const int d = gid & (DI - 1);
    const float4 w = *(const float4*)&cw[d * 4];
    float acc = cb[d];
    const float wj[4] = {w.x, w.y, w.z, w.w};
#pragma unroll
    for (int j = 0; j < 4; j++) {
        const int li = l + j - 3;
        if (li >= 0) acc = fmaf(xc[(size_t)li * DI + d], wj[j], acc);
    }
    xs[gid] = siluf_(acc);
}

// ---------------- GEMM2: xs[L,DI] @ Wx[DI,96] split-K -----------------
__global__ __launch_bounds__(256) void gemm2_splitk(const float* __restrict__ xs,
                                                    const float* __restrict__ Wx,
                                                    float* __restrict__ part) {
    __shared__ float As[32][64];
    __shared__ float Bs[32 * 96];
    const int tid = threadIdx.x;
    const int bm = blockIdx.x * 64;
    const int ks = blockIdx.y;
    const int ty = tid >> 4, tx = tid & 15;
    float acc[4][6];
#pragma unroll
    for (int i = 0; i < 4; i++)
#pragma unroll
        for (int j = 0; j < 6; j++) acc[i][j] = 0.f;

    for (int kt = 0; kt < G2KC; kt += 32) {
        const int kbase = ks * G2KC + kt;
        float4 av[2];
        int arr[2], akk[2];
#pragma unroll
        for (int i = 0; i < 2; i++) {
            const int f = tid + 256 * i;
            arr[i] = f >> 3;
            akk[i] = (f & 7) << 2;
            av[i] = *(const float4*)&xs[(size_t)(bm + arr[i]) * DI + kbase + akk[i]];
        }
        float4 bv[3];
        int bro[3], bco[3];
#pragma unroll
        for (int i = 0; i < 3; i++) {
            const int f = tid + 256 * i;
            bro[i] = (f << 2) / 96;
            bco[i] = (f << 2) % 96;
            bv[i] = *(const float4*)&Wx[(size_t)(kbase + bro[i]) * 96 + bco[i]];
        }
        __syncthreads();
#pragma unroll
        for (int i = 0; i < 2; i++) {
            As[akk[i] + 0][arr[i]] = av[i].x;
            As[akk[i] + 1][arr[i]] = av[i].y;
            As[akk[i] + 2][arr[i]] = av[i].z;
            As[akk[i] + 3][arr[i]] = av[i].w;
        }
#pragma unroll
        for (int i = 0; i < 3; i++)
            *(float4*)&Bs[bro[i] * 96 + bco[i]] = bv[i];
        __syncthreads();
#pragma unroll
        for (int k = 0; k < 32; k++) {
            float a[4], b[6];
            *(float4*)&a[0] = *(const float4*)&As[k][ty * 4];
            *(float2*)&b[0] = *(const float2*)&Bs[k * 96 + tx * 6];
            *(float2*)&b[2] = *(const float2*)&Bs[k * 96 + tx * 6 + 2];
            *(float2*)&b[4] = *(const float2*)&Bs[k * 96 + tx * 6 + 4];
#pragma unroll
            for (int i = 0; i < 4; i++)
#pragma unroll
                for (int j = 0; j < 6; j++) acc[i][j] = fmaf(a[i], b[j], acc[i][j]);
        }
    }
#pragma unroll
    for (int i = 0; i < 4; i++) {
        const int row = bm + ty * 4 + i;
#pragma unroll
        for (int j = 0; j < 6; j++) {
            part[((size_t)ks * LL + row) * NXDBL + tx * 6 + j] = acc[i][j];
        }
    }
}

__global__ __launch_bounds__(256) void gemm2_reduce(const float* __restrict__ part,
                                                    float* __restrict__ xdbl) {
    const int gid = blockIdx.x * 256 + threadIdx.x;
    if (gid < LL * NXDBL) {
        float s = 0.f;
#pragma unroll
        for (int ks = 0; ks < KSPLIT; ks++) s += part[(size_t)ks * LL * NXDBL + gid];
        xdbl[gid] = s;
    }
}

// ---------------- GEMM 64x64 tile fp32 (dt path, K=64) -----------------
template <int EPI>
__global__ __launch_bounds__(256) void gemm64(const float* __restrict__ A,
                                              const float* __restrict__ B,
                                              const float* __restrict__ bias,
                                              float* __restrict__ C,
                                              int M, int N, int K,
                                              int lda, int ldb, int ldc) {
    __shared__ float As[16][64];
    __shared__ float Bs[16][64];
    const int tid = threadIdx.x;
    const int bm = blockIdx.y * 64, bn = blockIdx.x * 64;
    const int ty = tid >> 4, tx = tid & 15;
    float acc[4][4];
#pragma unroll
    for (int i = 0; i < 4; i++)
#pragma unroll
        for (int j = 0; j < 4; j++) acc[i][j] = 0.f;

    const int ar = tid >> 2, ak = (tid & 3) << 2;
    const int bk = tid >> 4, bc2 = (tid & 15) << 2;

    for (int k0 = 0; k0 < K; k0 += 16) {
        float4 a0 = *(const float4*)&A[(size_t)(bm + ar) * lda + k0 + ak];
        float4 b0 = *(const float4*)&B[(size_t)(k0 + bk) * ldb + bn + bc2];
        __syncthreads();
        As[ak + 0][ar] = a0.x; As[ak + 1][ar] = a0.y;
        As[ak + 2][ar] = a0.z; As[ak + 3][ar] = a0.w;
        *(float4*)&Bs[bk][bc2] = b0;
        __syncthreads();
#pragma unroll
        for (int k = 0; k < 16; k++) {
            float a[4], b[4];
            *(float4*)&a[0] = *(const float4*)&As[k][ty * 4];
            *(float4*)&b[0] = *(const float4*)&Bs[k][tx * 4];
#pragma unroll
            for (int i = 0; i < 4; i++)
#pragma unroll
                for (int j = 0; j < 4; j++) acc[i][j] = fmaf(a[i], b[j], acc[i][j]);
        }
    }
#pragma unroll
    for (int i = 0; i < 4; i++) {
        const int row = bm + ty * 4 + i;
        const int col = bn + tx * 4;
        float4 v;
        if (EPI == 2) {
            v = make_float4(softplusf_(acc[i][0] + bias[col + 0]),
                            softplusf_(acc[i][1] + bias[col + 1]),
                            softplusf_(acc[i][2] + bias[col + 2]),
                            softplusf_(acc[i][3] + bias[col + 3]));
        } else {
            v = make_float4(acc[i][0], acc[i][1], acc[i][2], acc[i][3]);
        }
        *(float4*)&C[(size_t)row * ldc + col] = v;
    }
}

// ---------------- scan phase 1: per-chunk composition, 16 states/thread ---------
__global__ __launch_bounds__(256) void scan_phase1(const float* __restrict__ dt,
                                                   const float* __restrict__ xs,
                                                   const float* __restrict__ xdbl,
                                                   const float* __restrict__ A_log,
                                                   float* __restrict__ chA,
                                                   float* __restrict__ chB) {
    const int g = blockIdx.x * 256 + threadIdx.x;
    const int d = g & (DI - 1);
    const int c = g >> 11;
    float An2[NS], ap[NS], bc[NS];
    {
        float al[NS];
#pragma unroll
        for (int q = 0; q < 4; q++)
            *(float4*)&al[q * 4] = *(const float4*)&A_log[d * NS + q * 4];
#pragma unroll
        for (int n = 0; n < NS; n++) {
            An2[n] = -__expf(al[n]) * 1.44269504f;
            ap[n] = 1.f;
            bc[n] = 0.f;
        }
    }
    const int l0 = c * CHLEN;
    for (int l = l0; l < l0 + CHLEN; ++l) {
        const float dtv = dt[(size_t)l * DI + d];
        const float xsv = xs[(size_t)l * DI + d];
        const float dx = dtv * xsv;
        float bv[NS];
#pragma unroll
        for (int q = 0; q < 4; q++)
            *(float4*)&bv[q * 4] = *(const float4*)&xdbl[(size_t)l * NXDBL + DTR + q * 4];
#pragma unroll
        for (int n = 0; n < NS; n++) {
            const float al = __builtin_amdgcn_exp2f(dtv * An2[n]);
            ap[n] *= al;
            bc[n] = fmaf(al, bc[n], dx * bv[n]);
        }
    }
    const size_t o = ((size_t)c * DI + d) * NS;
#pragma unroll
    for (int q = 0; q < 4; q++) {
        *(float4*)&chA[o + q * 4] = *(float4*)&ap[q * 4];
        *(float4*)&chB[o + q * 4] = *(float4*)&bc[q * 4];
    }
}

// ---------------- scan phase 2: serial prefix over chunks (h0 in-place in chA) ---
__global__ __launch_bounds__(256) void scan_phase2(float* __restrict__ chA,
                                                   const float* __restrict__ chB,
                                                   float* __restrict__ hT_out) {
    const int t = blockIdx.x * 256 + threadIdx.x;  // 0..DI*NS-1
    float h = 0.f;
#pragma unroll 4
    for (int c = 0; c < NCHUNK; ++c) {
        const size_t o = (size_t)c * DI * NS + t;
        const float a = chA[o];
        const float b = chB[o];
        chA[o] = h;  // h0 for chunk c, overwrites a (already consumed)
        h = fmaf(a, h, b);
    }
    hT_out[t] = h;
}

// ---------------- scan phase 3: re-scan with h0, fused y epilogue (bf16 y) -------
__global__ __launch_bounds__(256) void scan_phase3(const float* __restrict__ dt,
                                                   const float* __restrict__ xs,
                                                   const float* __restrict__ xdbl,
                                                   const float* __restrict__ A_log,
                                                   const float* __restrict__ h0,
                                                   const float* __restrict__ Dw,
                                                   const float* __restrict__ res,
                                                   u16* __restrict__ yb) {
    const int g = blockIdx.x * 256 + threadIdx.x;
    const int d = g & (DI - 1);
    const int c = g >> 11;
    float An2[NS], h[NS];
    {
        float al[NS];
#pragma unroll
        for (int q = 0; q < 4; q++)
            *(float4*)&al[q * 4] = *(const float4*)&A_log[d * NS + q * 4];
#pragma unroll
        for (int n = 0; n < NS; n++) An2[n] = -__expf(al[n]) * 1.44269504f;
    }
    const size_t ho = ((size_t)c * DI + d) * NS;
#pragma unroll
    for (int q = 0; q < 4; q++) *(float4*)&h[q * 4] = *(const float4*)&h0[ho + q * 4];
    const float Dd = Dw[d];
    const int l0 = c * CHLEN;
    for (int l = l0; l < l0 + CHLEN; ++l) {
        const float dtv = dt[(size_t)l * DI + d];
        const float xsv = xs[(size_t)l * DI + d];
        const float resv = res[(size_t)l * DI + d];
        const float dx = dtv * xsv;
        float bv[NS], cv[NS];
#pragma unroll
        for (int q = 0; q < 4; q++) {
            *(float4*)&bv[q * 4] = *(const float4*)&xdbl[(size_t)l * NXDBL + DTR + q * 4];
            *(float4*)&cv[q * 4] =
                *(const float4*)&xdbl[(size_t)l * NXDBL + DTR + NS + q * 4];
        }
#pragma unroll
        for (int n = 0; n < NS; n++) {
            const float al = __builtin_amdgcn_exp2f(dtv * An2[n]);
            h[n] = fmaf(al, h[n], dx * bv[n]);
        }
        float y0 = 0.f, y1 = 0.f, y2 = 0.f, y3 = 0.f;
#pragma unroll
        for (int n = 0; n < NS; n += 4) {
            y0 = fmaf(h[n + 0], cv[n + 0], y0);
            y1 = fmaf(h[n + 1], cv[n + 1], y1);
            y2 = fmaf(h[n + 2], cv[n + 2], y2);
            y3 = fmaf(h[n + 3], cv[n + 3], y3);
        }
        float yv = ((y0 + y1) + (y2 + y3)) + xsv * Dd;
        yv *= siluf_(resv);
        yb[(size_t)l * DI + d] = f2b(yv);
    }
}

extern "C" void kernel_launch(void* const* d_in, const int* in_sizes, int n_in,
                              void* d_out, int out_size, void* d_ws, size_t ws_size,
                              hipStream_t stream) {
    const float* x = (const float*)d_in[0];
    const float* W_in = (const float*)d_in[1];
    const float* conv_w = (const float*)d_in[2];
    const float* conv_b = (const float*)d_in[3];
    const float* W_x = (const float*)d_in[4];
    const float* W_dt = (const float*)d_in[5];
    const float* b_dt = (const float*)d_in[6];
    const float* A_log = (const float*)d_in[7];
    const float* Dw = (const float*)d_in[8];
    const float* W_out = (const float*)d_in[9];
    float* out = (float*)d_out;

    float* ws = (float*)d_ws;
    float* xc = ws;                    // [0, 4194304)        L*DI f32 ; later yb (bf16)
    float* res = ws + 4194304;         // [4194304, 8388608)  L*DI f32 ; later GEMM4 partials
    float* xs = ws + 8388608;          // [8388608, 12582912) L*DI f32
    float* dt = ws + 12582912;         // [12582912,16777216) L*DI f32 ; earlier W_inT_b
    float* xdbl = ws + 16777216;       // [16777216,16973824) L*96 f32
    float* chA = ws + 16973824;        // [16973824,19070976) NCHUNK*DI*NS f32 (->h0)
    float* chB = ws + 19070976;        // [19070976,21168128) NCHUNK*DI*NS f32
                                       //   also hosts: xb, part, W_outT_b (disjoint)
    // aliased buffers:
    u16* xb = (u16*)chB;          // L*DM bf16 — live convert->gemm1
    float* part = chB;            // 8*L*96 f32 — live gemm2_splitk->reduce
    u16* W_outT_b = (u16*)chB;    // DM*DI bf16 — live after phase2
    u16* W_inT_b = (u16*)dt;      // 2DI*DM bf16 — dead before dt written
    u16* yb = (u16*)xc;           // L*DI bf16 — xc dead after conv_silu
    float* g4part = res;          // 2 * LL*DM f32 = 16MB — res dead after phase3

    // 1) bf16 converts for GEMM1
    convert_plain<<<(LL * DM) / 1024, 256, 0, stream>>>(x, xb);
    convert_T<<<dim3(2 * DI / 32, DM / 32), 256, 0, stream>>>(W_in, W_inT_b, DM, 2 * DI);
    // 2) x_and_res = x @ W_in  (bf16 MFMA) -> xc, res
    gemm_mfma<1><<<dim3(2 * DI / 128, LL / 128), 256, 0, stream>>>(xb, W_inT_b, xc, res,
                                                                   LL, 2 * DI, DM, DM);
    // 3) conv + silu -> xs
    conv_silu<<<(LL * DI) / 256, 256, 0, stream>>>(xc, conv_w, conv_b, xs);
    // 4) x_dbl = xs @ W_x (split-K + reduce)  (part overwrites xb — dead)
    gemm2_splitk<<<dim3(LL / 64, KSPLIT), 256, 0, stream>>>(xs, W_x, part);
    gemm2_reduce<<<(LL * NXDBL + 255) / 256, 256, 0, stream>>>(part, xdbl);
    // 5) dt = softplus(dt_r @ W_dt + b_dt)  (overwrites W_inT_b — dead)
    gemm64<2><<<dim3(DI / 64, LL / 64), 256, 0, stream>>>(xdbl, W_dt, b_dt, dt,
                                                          LL, DI, DTR, NXDBL, DI, DI);
    // 6) chunked scan (chB overwrites part — dead)
    scan_phase1<<<(DI * NCHUNK) / 256, 256, 0, stream>>>(dt, xs, xdbl, A_log, chA, chB);
    scan_phase2<<<(DI * NS) / 256, 256, 0, stream>>>(chA, chB, out + (size_t)LL * DM);
    // 7) W_out convert (chB dead after phase2) + scan phase 3 -> yb (bf16)
    convert_T<<<dim3(DM / 32, DI / 32), 256, 0, stream>>>(W_out, W_outT_b, DI, DM);
    scan_phase3<<<(DI * NCHUNK) / 256, 256, 0, stream>>>(dt, xs, xdbl, A_log, chA, Dw,
                                                         res, yb);
    // 8) out = y @ W_out (bf16 MFMA, split-K=2 over blockIdx.z; res now dead)
    gemm_mfma<0><<<dim3(DM / 128, LL / 128, 2), 256, 0, stream>>>(yb, W_outT_b, g4part,
                                                                  nullptr, LL, DM, DI,
                                                                  DI / 2);
    sum2<<<(LL * DM) / 1024, 256, 0, stream>>>(g4part, out, LL * DM);
}

// Round 5
// 231.970 us; speedup vs baseline: 2.4065x; 1.0237x over previous
//
#include <hip/hip_runtime.h>
#include <math.h>

#define DM 1024
#define DI 2048
#define NS 16
#define DTR 64
#define LL 2048
#define NXDBL 96      // DTR + 2*NS
#define NCHUNK 64
#define CHLEN 32      // LL / NCHUNK
#define KSPLIT 8
#define G2KC 256      // DI / KSPLIT

typedef unsigned short u16;
typedef __attribute__((ext_vector_type(8))) short short8;
typedef __attribute__((ext_vector_type(4))) float f32x4;

__device__ __forceinline__ float sigmoidf_(float x) { return 1.f / (1.f + __expf(-x)); }
__device__ __forceinline__ float siluf_(float x) { return x * sigmoidf_(x); }
__device__ __forceinline__ float softplusf_(float x) {
    return x > 0.f ? x + log1pf(__expf(-x)) : log1pf(__expf(x));
}
__device__ __forceinline__ u16 f2b(float f) {  // fp32 -> bf16 RNE
    unsigned u = __float_as_uint(f);
    return (u16)((u + 0x7FFFu + ((u >> 16) & 1u)) >> 16);
}

// ---------------- fp32 -> bf16 plain convert (4 elems/thread) -----------------
__global__ __launch_bounds__(256) void convert_plain(const float* __restrict__ src,
                                                     u16* __restrict__ dst) {
    const int i = (blockIdx.x * 256 + threadIdx.x) * 4;
    float4 v = *(const float4*)&src[i];
    u16 o[4] = {f2b(v.x), f2b(v.y), f2b(v.z), f2b(v.w)};
    *(ushort4*)&dst[i] = *(ushort4*)o;
}

// ---------------- fp32 [R][C] -> bf16 [C][R] transpose convert -----------------
__global__ __launch_bounds__(256) void convert_T(const float* __restrict__ src,
                                                 u16* __restrict__ dst, int R, int C) {
    __shared__ float t[32][33];
    const int tx = threadIdx.x & 31, ty = threadIdx.x >> 5;  // ty 0..7
    const int c0 = blockIdx.x * 32, r0 = blockIdx.y * 32;
#pragma unroll
    for (int i = 0; i < 4; i++)
        t[ty + i * 8][tx] = src[(size_t)(r0 + ty + i * 8) * C + c0 + tx];
    __syncthreads();
#pragma unroll
    for (int i = 0; i < 4; i++)
        dst[(size_t)(c0 + ty + i * 8) * R + r0 + tx] = f2b(t[tx][ty + i * 8]);
}

// ---------------- bf16 MFMA GEMM: C[M][N] = A[M][K] @ Bt[N][K]^T -----------------
// 128x128 tile, BK=32, K = NSTEPS*32. 3-buffer LDS pipeline, prefetch distance 2,
// counted s_waitcnt vmcnt(N) (never a full drain in steady state) + raw s_barrier.
// EPI==1: split cols [0,DI)->C0, [DI,2DI)->C1, both ld=DI.
// EPI==3: C0 = softplus(acc + bias[col]), ld=N.
// EPI==0: fp32 partial to C0 + blockIdx.z*M*N (split-K over gridDim.z).
#define WAITV(N) asm volatile("s_waitcnt vmcnt(" #N ")" ::: "memory")
template <int EPI, int NSTEPS>
__global__ __launch_bounds__(256) void gemm_mfma(const u16* __restrict__ A,
                                                 const u16* __restrict__ Bt,
                                                 float* __restrict__ C0,
                                                 float* __restrict__ C1,
                                                 const float* __restrict__ bias,
                                                 int M, int N, int lda) {
    __shared__ u16 As[3][128 * 32];
    __shared__ u16 Bs[3][128 * 32];
    const int tid = threadIdx.x;
    const int lane = tid & 63;
    const int wave = tid >> 6;
    const int bm = blockIdx.y * 128, bn = blockIdx.x * 128;
    const int wr = wave >> 1, wc = wave & 1;
    const int k_off = blockIdx.z * (NSTEPS * 32);

    f32x4 acc[4][4];
#pragma unroll
    for (int m = 0; m < 4; m++)
#pragma unroll
        for (int n = 0; n < 4; n++) acc[m][n] = (f32x4)0.f;

    const int srow = tid >> 2, skel = (tid & 3) << 3;
    const u16* Ag0 = A + (size_t)(bm + srow) * lda + k_off + skel;
    const u16* Ag1 = A + (size_t)(bm + 64 + srow) * lda + k_off + skel;
    const u16* Bg0 = Bt + (size_t)(bn + srow) * lda + k_off + skel;
    const u16* Bg1 = Bt + (size_t)(bn + 64 + srow) * lda + k_off + skel;
    u16* Asl = &As[0][0] + tid * 8;
    u16* Bsl = &Bs[0][0] + tid * 8;

    const int arow = (wr * 64 + (lane & 15)) * 32 + (lane >> 4) * 8;
    const int brow = (wc * 64 + (lane & 15)) * 32 + (lane >> 4) * 8;

#define STAGE(buf, ks)                                                               \
    do {                                                                             \
        __builtin_amdgcn_global_load_lds(                                            \
            (const __attribute__((address_space(1))) unsigned*)(Ag0 + (ks)),         \
            (__attribute__((address_space(3))) unsigned*)(Asl + (buf) * 4096),       \
            16, 0, 0);                                                               \
        __builtin_amdgcn_global_load_lds(                                            \
            (const __attribute__((address_space(1))) unsigned*)(Ag1 + (ks)),         \
            (__attribute__((address_space(3))) unsigned*)(Asl + (buf) * 4096 + 2048),\
            16, 0, 0);                                                               \
        __builtin_amdgcn_global_load_lds(                                            \
            (const __attribute__((address_space(1))) unsigned*)(Bg0 + (ks)),         \
            (__attribute__((address_space(3))) unsigned*)(Bsl + (buf) * 4096),       \
            16, 0, 0);                                                               \
        __builtin_amdgcn_global_load_lds(                                            \
            (const __attribute__((address_space(1))) unsigned*)(Bg1 + (ks)),         \
            (__attribute__((address_space(3))) unsigned*)(Bsl + (buf) * 4096 + 2048),\
            16, 0, 0);                                                               \
    } while (0)

#define COMPUTE(buf)                                                                 \
    do {                                                                             \
        short8 av[4], bv[4];                                                         \
        _Pragma("unroll") for (int m = 0; m < 4; m++)                                \
            av[m] = *(const short8*)&As[buf][arow + m * 512];                        \
        _Pragma("unroll") for (int n = 0; n < 4; n++)                                \
            bv[n] = *(const short8*)&Bs[buf][brow + n * 512];                        \
        _Pragma("unroll") for (int m = 0; m < 4; m++)                                \
            _Pragma("unroll") for (int n = 0; n < 4; n++)                            \
                acc[m][n] = __builtin_amdgcn_mfma_f32_16x16x32_bf16(av[m], bv[n],    \
                                                                    acc[m][n], 0, 0, 0); \
    } while (0)

    STAGE(0, 0);
    if (NSTEPS > 1) STAGE(1, 32);
#pragma unroll
    for (int s = 0; s < NSTEPS; ++s) {
        if (s + 2 < NSTEPS) {
            STAGE((s + 2) % 3, (s + 2) * 32);
            WAITV(8);                      // oldest 4 (tile s) complete; 8 in flight
        } else if (s + 1 < NSTEPS) {
            WAITV(4);                      // only tile s+1's 4 remain
        } else {
            WAITV(0);
        }
        __builtin_amdgcn_s_barrier();      // all waves' slices of tile s visible
        COMPUTE(s % 3);
        __builtin_amdgcn_s_barrier();      // protect buf (s%3)==( s+3 )%3 from overwrite
    }
#undef STAGE
#undef COMPUTE

    const int crow0 = bm + wr * 64 + (lane >> 4) * 4;
    const int ccol0 = bn + wc * 64 + (lane & 15);
    float* C0z = C0 + (size_t)blockIdx.z * M * N;
#pragma unroll
    for (int m = 0; m < 4; m++)
#pragma unroll
        for (int n = 0; n < 4; n++) {
            const int col = ccol0 + n * 16;
#pragma unroll
            for (int r = 0; r < 4; r++) {
                const int row = crow0 + m * 16 + r;
                const float v = acc[m][n][r];
                if (EPI == 1) {
                    if (col < DI)
                        C0[(size_t)row * DI + col] = v;
                    else
                        C1[(size_t)row * DI + col - DI] = v;
                } else if (EPI == 3) {
                    C0[(size_t)row * N + col] = softplusf_(v + bias[col]);
                } else {
                    C0z[(size_t)row * N + col] = v;
                }
            }
        }
}

// ---------------- sum of 2 split-K partials -----------------
__global__ __launch_bounds__(256) void sum2(const float* __restrict__ p,
                                            float* __restrict__ out, int n) {
    const int i = (blockIdx.x * 256 + threadIdx.x) * 4;
    float4 a = *(const float4*)&p[i];
    float4 b = *(const float4*)&p[(size_t)n + i];
    float4 o = make_float4(a.x + b.x, a.y + b.y, a.z + b.z, a.w + b.w);
    *(float4*)&out[i] = o;
}

// ---------------- conv (k=4, causal) + silu -----------------
__global__ __launch_bounds__(256) void conv_silu(const float* __restrict__ xc,
                                                 const float* __restrict__ cw,
                                                 const float* __restrict__ cb,
                                                 float* __restrict__ xs) {
    const int gid = blockIdx.x * 256 + threadIdx.x;  // l*DI + d
    const int l = gid >> 11;
    const int d = gid & (DI - 1);
    const float4 w = *(const float4*)&cw[d * 4];
    float acc = cb[d];
    const float wj[4] = {w.x, w.y, w.z, w.w};
#pragma unroll
    for (int j = 0; j < 4; j++) {
        const int li = l + j - 3;
        if (li >= 0) acc = fmaf(xc[(size_t)li * DI + d], wj[j], acc);
    }
    xs[gid] = siluf_(acc);
}

// ---------------- GEMM2: xs[L,DI] @ Wx[DI,96] split-K -----------------
__global__ __launch_bounds__(256) void gemm2_splitk(const float* __restrict__ xs,
                                                    const float* __restrict__ Wx,
                                                    float* __restrict__ part) {
    __shared__ float As[32][64];
    __shared__ float Bs[32 * 96];
    const int tid = threadIdx.x;
    const int bm = blockIdx.x * 64;
    const int ks = blockIdx.y;
    const int ty = tid >> 4, tx = tid & 15;
    float acc[4][6];
#pragma unroll
    for (int i = 0; i < 4; i++)
#pragma unroll
        for (int j = 0; j < 6; j++) acc[i][j] = 0.f;

    for (int kt = 0; kt < G2KC; kt += 32) {
        const int kbase = ks * G2KC + kt;
        float4 av[2];
        int arr[2], akk[2];
#pragma unroll
        for (int i = 0; i < 2; i++) {
            const int f = tid + 256 * i;
            arr[i] = f >> 3;
            akk[i] = (f & 7) << 2;
            av[i] = *(const float4*)&xs[(size_t)(bm + arr[i]) * DI + kbase + akk[i]];
        }
        float4 bv[3];
        int bro[3], bco[3];
#pragma unroll
        for (int i = 0; i < 3; i++) {
            const int f = tid + 256 * i;
            bro[i] = (f << 2) / 96;
            bco[i] = (f << 2) % 96;
            bv[i] = *(const float4*)&Wx[(size_t)(kbase + bro[i]) * 96 + bco[i]];
        }
        __syncthreads();
#pragma unroll
        for (int i = 0; i < 2; i++) {
            As[akk[i] + 0][arr[i]] = av[i].x;
            As[akk[i] + 1][arr[i]] = av[i].y;
            As[akk[i] + 2][arr[i]] = av[i].z;
            As[akk[i] + 3][arr[i]] = av[i].w;
        }
#pragma unroll
        for (int i = 0; i < 3; i++)
            *(float4*)&Bs[bro[i] * 96 + bco[i]] = bv[i];
        __syncthreads();
#pragma unroll
        for (int k = 0; k < 32; k++) {
            float a[4], b[6];
            *(float4*)&a[0] = *(const float4*)&As[k][ty * 4];
            *(float2*)&b[0] = *(const float2*)&Bs[k * 96 + tx * 6];
            *(float2*)&b[2] = *(const float2*)&Bs[k * 96 + tx * 6 + 2];
            *(float2*)&b[4] = *(const float2*)&Bs[k * 96 + tx * 6 + 4];
#pragma unroll
            for (int i = 0; i < 4; i++)
#pragma unroll
                for (int j = 0; j < 6; j++) acc[i][j] = fmaf(a[i], b[j], acc[i][j]);
        }
    }
#pragma unroll
    for (int i = 0; i < 4; i++) {
        const int row = bm + ty * 4 + i;
#pragma unroll
        for (int j = 0; j < 6; j++) {
            part[((size_t)ks * LL + row) * NXDBL + tx * 6 + j] = acc[i][j];
        }
    }
}

// reduce + emit bf16 copy of the dt_r columns (cols 0..63) for the MFMA dt-GEMM
__global__ __launch_bounds__(256) void gemm2_reduce(const float* __restrict__ part,
                                                    float* __restrict__ xdbl,
                                                    u16* __restrict__ dtr_b) {
    const int gid = blockIdx.x * 256 + threadIdx.x;
    if (gid < LL * NXDBL) {
        float s = 0.f;
#pragma unroll
        for (int ks = 0; ks < KSPLIT; ks++) s += part[(size_t)ks * LL * NXDBL + gid];
        xdbl[gid] = s;
        const int row = gid / NXDBL;
        const int col = gid - row * NXDBL;
        if (col < DTR) dtr_b[row * DTR + col] = f2b(s);
    }
}

// ---------------- scan phase 1: per-chunk composition, 16 states/thread ---------
__global__ __launch_bounds__(256) void scan_phase1(const float* __restrict__ dt,
                                                   const float* __restrict__ xs,
                                                   const float* __restrict__ xdbl,
                                                   const float* __restrict__ A_log,
                                                   float* __restrict__ chA,
                                                   float* __restrict__ chB) {
    const int g = blockIdx.x * 256 + threadIdx.x;
    const int d = g & (DI - 1);
    const int c = g >> 11;
    float An2[NS], ap[NS], bc[NS];
    {
        float al[NS];
#pragma unroll
        for (int q = 0; q < 4; q++)
            *(float4*)&al[q * 4] = *(const float4*)&A_log[d * NS + q * 4];
#pragma unroll
        for (int n = 0; n < NS; n++) {
            An2[n] = -__expf(al[n]) * 1.44269504f;
            ap[n] = 1.f;
            bc[n] = 0.f;
        }
    }
    const int l0 = c * CHLEN;
    for (int l = l0; l < l0 + CHLEN; ++l) {
        const float dtv = dt[(size_t)l * DI + d];
        const float xsv = xs[(size_t)l * DI + d];
        const float dx = dtv * xsv;
        float bv[NS];
#pragma unroll
        for (int q = 0; q < 4; q++)
            *(float4*)&bv[q * 4] = *(const float4*)&xdbl[(size_t)l * NXDBL + DTR + q * 4];
#pragma unroll
        for (int n = 0; n < NS; n++) {
            const float al = __builtin_amdgcn_exp2f(dtv * An2[n]);
            ap[n] *= al;
            bc[n] = fmaf(al, bc[n], dx * bv[n]);
        }
    }
    const size_t o = ((size_t)c * DI + d) * NS;
#pragma unroll
    for (int q = 0; q < 4; q++) {
        *(float4*)&chA[o + q * 4] = *(float4*)&ap[q * 4];
        *(float4*)&chB[o + q * 4] = *(float4*)&bc[q * 4];
    }
}

// ---------------- scan phase 2: serial prefix over chunks (h0 in-place in chA) ---
__global__ __launch_bounds__(256) void scan_phase2(float* __restrict__ chA,
                                                   const float* __restrict__ chB,
                                                   float* __restrict__ hT_out) {
    const int t = blockIdx.x * 256 + threadIdx.x;  // 0..DI*NS-1
    float h = 0.f;
#pragma unroll 4
    for (int c = 0; c < NCHUNK; ++c) {
        const size_t o = (size_t)c * DI * NS + t;
        const float a = chA[o];
        const float b = chB[o];
        chA[o] = h;  // h0 for chunk c, overwrites a (already consumed)
        h = fmaf(a, h, b);
    }
    hT_out[t] = h;
}

// ---------------- scan phase 3: re-scan with h0, fused y epilogue (bf16 y) -------
__global__ __launch_bounds__(256) void scan_phase3(const float* __restrict__ dt,
                                                   const float* __restrict__ xs,
                                                   const float* __restrict__ xdbl,
                                                   const float* __restrict__ A_log,
                                                   const float* __restrict__ h0,
                                                   const float* __restrict__ Dw,
                                                   const float* __restrict__ res,
                                                   u16* __restrict__ yb) {
    const int g = blockIdx.x * 256 + threadIdx.x;
    const int d = g & (DI - 1);
    const int c = g >> 11;
    float An2[NS], h[NS];
    {
        float al[NS];
#pragma unroll
        for (int q = 0; q < 4; q++)
            *(float4*)&al[q * 4] = *(const float4*)&A_log[d * NS + q * 4];
#pragma unroll
        for (int n = 0; n < NS; n++) An2[n] = -__expf(al[n]) * 1.44269504f;
    }
    const size_t ho = ((size_t)c * DI + d) * NS;
#pragma unroll
    for (int q = 0; q < 4; q++) *(float4*)&h[q * 4] = *(const float4*)&h0[ho + q * 4];
    const float Dd = Dw[d];
    const int l0 = c * CHLEN;
    for (int l = l0; l < l0 + CHLEN; ++l) {
        const float dtv = dt[(size_t)l * DI + d];
        const float xsv = xs[(size_t)l * DI + d];
        const float resv = res[(size_t)l * DI + d];
        const float dx = dtv * xsv;
        float bv[NS], cv[NS];
#pragma unroll
        for (int q = 0; q < 4; q++) {
            *(float4*)&bv[q * 4] = *(const float4*)&xdbl[(size_t)l * NXDBL + DTR + q * 4];
            *(float4*)&cv[q * 4] =
                *(const float4*)&xdbl[(size_t)l * NXDBL + DTR + NS + q * 4];
        }
#pragma unroll
        for (int n = 0; n < NS; n++) {
            const float al = __builtin_amdgcn_exp2f(dtv * An2[n]);
            h[n] = fmaf(al, h[n], dx * bv[n]);
        }
        float y0 = 0.f, y1 = 0.f, y2 = 0.f, y3 = 0.f;
#pragma unroll
        for (int n = 0; n < NS; n += 4) {
            y0 = fmaf(h[n + 0], cv[n + 0], y0);
            y1 = fmaf(h[n + 1], cv[n + 1], y1);
            y2 = fmaf(h[n + 2], cv[n + 2], y2);
            y3 = fmaf(h[n + 3], cv[n + 3], y3);
        }
        float yv = ((y0 + y1) + (y2 + y3)) + xsv * Dd;
        yv *= siluf_(resv);
        yb[(size_t)l * DI + d] = f2b(yv);
    }
}

extern "C" void kernel_launch(void* const* d_in, const int* in_sizes, int n_in,
                              void* d_out, int out_size, void* d_ws, size_t ws_size,
                              hipStream_t stream) {
    const float* x = (const float*)d_in[0];
    const float* W_in = (const float*)d_in[1];
    const float* conv_w = (const float*)d_in[2];
    const float* conv_b = (const float*)d_in[3];
    const float* W_x = (const float*)d_in[4];
    const float* W_dt = (const float*)d_in[5];
    const float* b_dt = (const float*)d_in[6];
    const float* A_log = (const float*)d_in[7];
    const float* Dw = (const float*)d_in[8];
    const float* W_out = (const float*)d_in[9];
    float* out = (float*)d_out;

    float* ws = (float*)d_ws;
    float* xc = ws;                    // [0, 4194304)        L*DI f32 ; later dtr_b/W_dtT_b/yb
    float* res = ws + 4194304;         // [4194304, 8388608)  L*DI f32 ; later GEMM4 partials
    float* xs = ws + 8388608;          // [8388608, 12582912) L*DI f32
    float* dt = ws + 12582912;         // [12582912,16777216) L*DI f32 ; earlier W_inT_b
    float* xdbl = ws + 16777216;       // [16777216,16973824) L*96 f32
    float* chA = ws + 16973824;        // [16973824,19070976) NCHUNK*DI*NS f32 (->h0)
    float* chB = ws + 19070976;        // [19070976,21168128) NCHUNK*DI*NS f32
                                       //   also hosts: xb, part, W_outT_b (disjoint lives)
    // aliased buffers:
    u16* xb = (u16*)chB;          // L*DM bf16 — live convert->gemm1
    float* part = chB;            // 8*L*96 f32 — live gemm2_splitk->reduce
    u16* W_outT_b = (u16*)chB;    // DM*DI bf16 — live after phase2
    u16* W_inT_b = (u16*)dt;      // 2DI*DM bf16 — dead before dt written
    u16* dtr_b = (u16*)xc;        // L*64 bf16   — xc dead after conv_silu
    u16* W_dtT_b = (u16*)(xc + 65536);  // DI*64 bf16 — same window
    u16* yb = (u16*)xc;           // L*DI bf16 — written at scan_phase3 (dtr dead)
    float* g4part = res;          // 2 * LL*DM f32 = 16MB — res dead after phase3

    // 1) bf16 converts for GEMM1
    convert_plain<<<(LL * DM) / 1024, 256, 0, stream>>>(x, xb);
    convert_T<<<dim3(2 * DI / 32, DM / 32), 256, 0, stream>>>(W_in, W_inT_b, DM, 2 * DI);
    // 2) x_and_res = x @ W_in  (bf16 MFMA) -> xc, res
    gemm_mfma<1, DM / 32><<<dim3(2 * DI / 128, LL / 128), 256, 0, stream>>>(
        xb, W_inT_b, xc, res, nullptr, LL, 2 * DI, DM);
    // 3) conv + silu -> xs
    conv_silu<<<(LL * DI) / 256, 256, 0, stream>>>(xc, conv_w, conv_b, xs);
    // 4) W_dt transpose-convert (xc region now dead)
    convert_T<<<dim3(DI / 32, DTR / 32), 256, 0, stream>>>(W_dt, W_dtT_b, DTR, DI);
    // 5) x_dbl = xs @ W_x (split-K + reduce; part overwrites xb — dead)
    gemm2_splitk<<<dim3(LL / 64, KSPLIT), 256, 0, stream>>>(xs, W_x, part);
    gemm2_reduce<<<(LL * NXDBL + 255) / 256, 256, 0, stream>>>(part, xdbl, dtr_b);
    // 6) dt = softplus(dt_r @ W_dt + b_dt)  (bf16 MFMA; overwrites W_inT_b — dead)
    gemm_mfma<3, DTR / 32><<<dim3(DI / 128, LL / 128), 256, 0, stream>>>(
        dtr_b, W_dtT_b, dt, nullptr, b_dt, LL, DI, DTR);
    // 7) chunked scan (chB overwrites part — dead)
    scan_phase1<<<(DI * NCHUNK) / 256, 256, 0, stream>>>(dt, xs, xdbl, A_log, chA, chB);
    scan_phase2<<<(DI * NS) / 256, 256, 0, stream>>>(chA, chB, out + (size_t)LL * DM);
    // 8) W_out convert (chB dead after phase2) + scan phase 3 -> yb (bf16)
    convert_T<<<dim3(DM / 32, DI / 32), 256, 0, stream>>>(W_out, W_outT_b, DI, DM);
    scan_phase3<<<(DI * NCHUNK) / 256, 256, 0, stream>>>(dt, xs, xdbl, A_log, chA, Dw,
                                                         res, yb);
    // 9) out = y @ W_out (bf16 MFMA, split-K=2 over blockIdx.z; res now dead)
    gemm_mfma<0, DI / 64><<<dim3(DM / 128, LL / 128, 2), 256, 0, stream>>>(
        yb, W_outT_b, g4part, nullptr, nullptr, LL, DM, DI);
    sum2<<<(LL * DM) / 1024, 256, 0, stream>>>(g4part, out, LL * DM);
}

// Round 6
// 201.724 us; speedup vs baseline: 2.7673x; 1.1499x over previous
//
#include <hip/hip_runtime.h>
#include <math.h>

#define DM 1024
#define DI 2048
#define NS 16
#define DTR 64
#define LL 2048
#define NXDBL 96      // DTR + 2*NS
#define NCHUNK 64
#define CHLEN 32      // LL / NCHUNK
#define KSPLIT 8
#define G2KC 256      // DI / KSPLIT

typedef unsigned short u16;
typedef __attribute__((ext_vector_type(8))) short short8;
typedef __attribute__((ext_vector_type(4))) float f32x4;

__device__ __forceinline__ float sigmoidf_(float x) { return 1.f / (1.f + __expf(-x)); }
__device__ __forceinline__ float siluf_(float x) { return x * sigmoidf_(x); }
__device__ __forceinline__ float softplus_fast(float x) {
    // max(x,0) + log(1 + exp(-|x|)); v_exp+v_log, abs err ~1e-6
    return fmaxf(x, 0.f) + __logf(1.f + __expf(-fabsf(x)));
}
__device__ __forceinline__ u16 f2b(float f) {  // fp32 -> bf16 RNE
    unsigned u = __float_as_uint(f);
    return (u16)((u + 0x7FFFu + ((u >> 16) & 1u)) >> 16);
}

// ---------------- fp32 -> bf16 plain convert (4 elems/thread) -----------------
__global__ __launch_bounds__(256) void convert_plain(const float* __restrict__ src,
                                                     u16* __restrict__ dst) {
    const int i = (blockIdx.x * 256 + threadIdx.x) * 4;
    float4 v = *(const float4*)&src[i];
    u16 o[4] = {f2b(v.x), f2b(v.y), f2b(v.z), f2b(v.w)};
    *(ushort4*)&dst[i] = *(ushort4*)o;
}

// ---------------- fp32 [R][C] -> bf16 [C][R] transpose convert -----------------
__global__ __launch_bounds__(256) void convert_T(const float* __restrict__ src,
                                                 u16* __restrict__ dst, int R, int C) {
    __shared__ float t[32][33];
    const int tx = threadIdx.x & 31, ty = threadIdx.x >> 5;  // ty 0..7
    const int c0 = blockIdx.x * 32, r0 = blockIdx.y * 32;
#pragma unroll
    for (int i = 0; i < 4; i++)
        t[ty + i * 8][tx] = src[(size_t)(r0 + ty + i * 8) * C + c0 + tx];
    __syncthreads();
#pragma unroll
    for (int i = 0; i < 4; i++)
        dst[(size_t)(c0 + ty + i * 8) * R + r0 + tx] = f2b(t[tx][ty + i * 8]);
}

// ---------------- bf16 MFMA GEMM: C[M][N] = A[M][K] @ Bt[N][K]^T -----------------
// 128x128 tile, BK=32, K = NSTEPS*32. 3-buffer LDS pipeline, prefetch distance 2,
// counted s_waitcnt vmcnt(N) (never a full drain in steady state) + raw s_barrier.
// EPI==1: split cols [0,DI)->C0, [DI,2DI)->C1, both ld=DI.
// EPI==0: fp32 partial to C0 + blockIdx.z*M*N (split-K over gridDim.z).
#define WAITV(N) asm volatile("s_waitcnt vmcnt(" #N ")" ::: "memory")
template <int EPI, int NSTEPS>
__global__ __launch_bounds__(256) void gemm_mfma(const u16* __restrict__ A,
                                                 const u16* __restrict__ Bt,
                                                 float* __restrict__ C0,
                                                 float* __restrict__ C1,
                                                 int M, int N, int lda) {
    __shared__ u16 As[3][128 * 32];
    __shared__ u16 Bs[3][128 * 32];
    const int tid = threadIdx.x;
    const int lane = tid & 63;
    const int wave = tid >> 6;
    const int bm = blockIdx.y * 128, bn = blockIdx.x * 128;
    const int wr = wave >> 1, wc = wave & 1;
    const int k_off = blockIdx.z * (NSTEPS * 32);

    f32x4 acc[4][4];
#pragma unroll
    for (int m = 0; m < 4; m++)
#pragma unroll
        for (int n = 0; n < 4; n++) acc[m][n] = (f32x4)0.f;

    const int srow = tid >> 2, skel = (tid & 3) << 3;
    const u16* Ag0 = A + (size_t)(bm + srow) * lda + k_off + skel;
    const u16* Ag1 = A + (size_t)(bm + 64 + srow) * lda + k_off + skel;
    const u16* Bg0 = Bt + (size_t)(bn + srow) * lda + k_off + skel;
    const u16* Bg1 = Bt + (size_t)(bn + 64 + srow) * lda + k_off + skel;
    u16* Asl = &As[0][0] + tid * 8;
    u16* Bsl = &Bs[0][0] + tid * 8;

    const int arow = (wr * 64 + (lane & 15)) * 32 + (lane >> 4) * 8;
    const int brow = (wc * 64 + (lane & 15)) * 32 + (lane >> 4) * 8;

#define STAGE(buf, ks)                                                               \
    do {                                                                             \
        __builtin_amdgcn_global_load_lds(                                            \
            (const __attribute__((address_space(1))) unsigned*)(Ag0 + (ks)),         \
            (__attribute__((address_space(3))) unsigned*)(Asl + (buf) * 4096),       \
            16, 0, 0);                                                               \
        __builtin_amdgcn_global_load_lds(                                            \
            (const __attribute__((address_space(1))) unsigned*)(Ag1 + (ks)),         \
            (__attribute__((address_space(3))) unsigned*)(Asl + (buf) * 4096 + 2048),\
            16, 0, 0);                                                               \
        __builtin_amdgcn_global_load_lds(                                            \
            (const __attribute__((address_space(1))) unsigned*)(Bg0 + (ks)),         \
            (__attribute__((address_space(3))) unsigned*)(Bsl + (buf) * 4096),       \
            16, 0, 0);                                                               \
        __builtin_amdgcn_global_load_lds(                                            \
            (const __attribute__((address_space(1))) unsigned*)(Bg1 + (ks)),         \
            (__attribute__((address_space(3))) unsigned*)(Bsl + (buf) * 4096 + 2048),\
            16, 0, 0);                                                               \
    } while (0)

#define COMPUTE(buf)                                                                 \
    do {                                                                             \
        short8 av[4], bv[4];                                                         \
        _Pragma("unroll") for (int m = 0; m < 4; m++)                                \
            av[m] = *(const short8*)&As[buf][arow + m * 512];                        \
        _Pragma("unroll") for (int n = 0; n < 4; n++)                                \
            bv[n] = *(const short8*)&Bs[buf][brow + n * 512];                        \
        _Pragma("unroll") for (int m = 0; m < 4; m++)                                \
            _Pragma("unroll") for (int n = 0; n < 4; n++)                            \
                acc[m][n] = __builtin_amdgcn_mfma_f32_16x16x32_bf16(av[m], bv[n],    \
                                                                    acc[m][n], 0, 0, 0); \
    } while (0)

    STAGE(0, 0);
    if (NSTEPS > 1) STAGE(1, 32);
#pragma unroll
    for (int s = 0; s < NSTEPS; ++s) {
        if (s + 2 < NSTEPS) {
            STAGE((s + 2) % 3, (s + 2) * 32);
            WAITV(8);                      // oldest 4 (tile s) complete; 8 in flight
        } else if (s + 1 < NSTEPS) {
            WAITV(4);                      // only tile s+1's 4 remain
        } else {
            WAITV(0);
        }
        __builtin_amdgcn_s_barrier();      // all waves' slices of tile s visible
        COMPUTE(s % 3);
        __builtin_amdgcn_s_barrier();      // protect buf (s%3) from next overwrite
    }
#undef STAGE
#undef COMPUTE

    const int crow0 = bm + wr * 64 + (lane >> 4) * 4;
    const int ccol0 = bn + wc * 64 + (lane & 15);
    float* C0z = C0 + (size_t)blockIdx.z * M * N;
#pragma unroll
    for (int m = 0; m < 4; m++)
#pragma unroll
        for (int n = 0; n < 4; n++) {
            const int col = ccol0 + n * 16;
#pragma unroll
            for (int r = 0; r < 4; r++) {
                const int row = crow0 + m * 16 + r;
                const float v = acc[m][n][r];
                if (EPI == 1) {
                    if (col < DI)
                        C0[(size_t)row * DI + col] = v;
                    else
                        C1[(size_t)row * DI + col - DI] = v;
                } else {
                    C0z[(size_t)row * N + col] = v;
                }
            }
        }
}

// ---------------- fp32 GEMM 128x128 tile, 8x8 micro, BK=16: dt path (K=64) -------
// C = softplus_fast(A@B + bias[col]); A lda=96 (xdbl cols 0..63), B=W_dt ldb=N.
__global__ __launch_bounds__(256) void gemm128_dt(const float* __restrict__ A,
                                                  const float* __restrict__ B,
                                                  const float* __restrict__ bias,
                                                  float* __restrict__ C,
                                                  int N, int K, int lda) {
    __shared__ float As[16][128];
    __shared__ float Bs[16][128];
    const int tid = threadIdx.x;
    const int bm = blockIdx.y * 128, bn = blockIdx.x * 128;
    const int ty = tid >> 4, tx = tid & 15;
    float acc[8][8];
#pragma unroll
    for (int i = 0; i < 8; i++)
#pragma unroll
        for (int j = 0; j < 8; j++) acc[i][j] = 0.f;

    const int ar = tid >> 2, ak = (tid & 3) << 2;
    const int bk = tid >> 5, bc = (tid & 31) << 2;

    for (int k0 = 0; k0 < K; k0 += 16) {
        float4 a0 = *(const float4*)&A[(size_t)(bm + ar) * lda + k0 + ak];
        float4 a1 = *(const float4*)&A[(size_t)(bm + ar + 64) * lda + k0 + ak];
        float4 b0 = *(const float4*)&B[(size_t)(k0 + bk) * N + bn + bc];
        float4 b1 = *(const float4*)&B[(size_t)(k0 + bk + 8) * N + bn + bc];
        __syncthreads();
        As[ak + 0][ar] = a0.x; As[ak + 1][ar] = a0.y;
        As[ak + 2][ar] = a0.z; As[ak + 3][ar] = a0.w;
        As[ak + 0][ar + 64] = a1.x; As[ak + 1][ar + 64] = a1.y;
        As[ak + 2][ar + 64] = a1.z; As[ak + 3][ar + 64] = a1.w;
        *(float4*)&Bs[bk][bc] = b0;
        *(float4*)&Bs[bk + 8][bc] = b1;
        __syncthreads();
#pragma unroll
        for (int k = 0; k < 16; k++) {
            float a[8], b[8];
            *(float4*)&a[0] = *(const float4*)&As[k][ty * 8];
            *(float4*)&a[4] = *(const float4*)&As[k][ty * 8 + 4];
            *(float4*)&b[0] = *(const float4*)&Bs[k][tx * 8];
            *(float4*)&b[4] = *(const float4*)&Bs[k][tx * 8 + 4];
#pragma unroll
            for (int i = 0; i < 8; i++)
#pragma unroll
                for (int j = 0; j < 8; j++) acc[i][j] = fmaf(a[i], b[j], acc[i][j]);
        }
    }
#pragma unroll
    for (int i = 0; i < 8; i++) {
        const int row = bm + ty * 8 + i;
#pragma unroll
        for (int j = 0; j < 8; j += 4) {
            const int col = bn + tx * 8 + j;
            const float4 bi = *(const float4*)&bias[col];
            float4 v = make_float4(softplus_fast(acc[i][j] + bi.x),
                                   softplus_fast(acc[i][j + 1] + bi.y),
                                   softplus_fast(acc[i][j + 2] + bi.z),
                                   softplus_fast(acc[i][j + 3] + bi.w));
            *(float4*)&C[(size_t)row * N + col] = v;
        }
    }
}

// ---------------- sum of 2 split-K partials -----------------
__global__ __launch_bounds__(256) void sum2(const float* __restrict__ p,
                                            float* __restrict__ out, int n) {
    const int i = (blockIdx.x * 256 + threadIdx.x) * 4;
    float4 a = *(const float4*)&p[i];
    float4 b = *(const float4*)&p[(size_t)n + i];
    float4 o = make_float4(a.x + b.x, a.y + b.y, a.z + b.z, a.w + b.w);
    *(float4*)&out[i] = o;
}

// ---------------- conv (k=4, causal) + silu -----------------
__global__ __launch_bounds__(256) void conv_silu(const float* __restrict__ xc,
                                                 const float* __restrict__ cw,
                                                 const float* __restrict__ cb,
                                                 float* __restrict__ xs) {
    const int gid = blockIdx.x * 256 + threadIdx.x;  // l*DI + d
    const int l = gid >> 11;
    const int d = gid & (DI - 1);
    const float4 w = *(const float4*)&cw[d * 4];
    float acc = cb[d];
    const float wj[4] = {w.x, w.y, w.z, w.w};
#pragma unroll
    for (int j = 0; j < 4; j++) {
        const int li = l + j - 3;
        if (li >= 0) acc = fmaf(xc[(size_t)li * DI + d], wj[j], acc);
    }
    xs[gid] = siluf_(acc);
}

// ---------------- GEMM2: xs[L,DI] @ Wx[DI,96] split-K -----------------
__global__ __launch_bounds__(256) void gemm2_splitk(const float* __restrict__ xs,
                                                    const float* __restrict__ Wx,
                                                    float* __restrict__ part) {
    __shared__ float As[32][64];
    __shared__ float Bs[32 * 96];
    const int tid = threadIdx.x;
    const int bm = blockIdx.x * 64;
    const int ks = blockIdx.y;
    const int ty = tid >> 4, tx = tid & 15;
    float acc[4][6];
#pragma unroll
    for (int i = 0; i < 4; i++)
#pragma unroll
        for (int j = 0; j < 6; j++) acc[i][j] = 0.f;

    for (int kt = 0; kt < G2KC; kt += 32) {
        const int kbase = ks * G2KC + kt;
        float4 av[2];
        int arr[2], akk[2];
#pragma unroll
        for (int i = 0; i < 2; i++) {
            const int f = tid + 256 * i;
            arr[i] = f >> 3;
            akk[i] = (f & 7) << 2;
            av[i] = *(const float4*)&xs[(size_t)(bm + arr[i]) * DI + kbase + akk[i]];
        }
        float4 bv[3];
        int bro[3], bco[3];
#pragma unroll
        for (int i = 0; i < 3; i++) {
            const int f = tid + 256 * i;
            bro[i] = (f << 2) / 96;
            bco[i] = (f << 2) % 96;
            bv[i] = *(const float4*)&Wx[(size_t)(kbase + bro[i]) * 96 + bco[i]];
        }
        __syncthreads();
#pragma unroll
        for (int i = 0; i < 2; i++) {
            As[akk[i] + 0][arr[i]] = av[i].x;
            As[akk[i] + 1][arr[i]] = av[i].y;
            As[akk[i] + 2][arr[i]] = av[i].z;
            As[akk[i] + 3][arr[i]] = av[i].w;
        }
#pragma unroll
        for (int i = 0; i < 3; i++)
            *(float4*)&Bs[bro[i] * 96 + bco[i]] = bv[i];
        __syncthreads();
#pragma unroll
        for (int k = 0; k < 32; k++) {
            float a[4], b[6];
            *(float4*)&a[0] = *(const float4*)&As[k][ty * 4];
            *(float2*)&b[0] = *(const float2*)&Bs[k * 96 + tx * 6];
            *(float2*)&b[2] = *(const float2*)&Bs[k * 96 + tx * 6 + 2];
            *(float2*)&b[4] = *(const float2*)&Bs[k * 96 + tx * 6 + 4];
#pragma unroll
            for (int i = 0; i < 4; i++)
#pragma unroll
                for (int j = 0; j < 6; j++) acc[i][j] = fmaf(a[i], b[j], acc[i][j]);
        }
    }
#pragma unroll
    for (int i = 0; i < 4; i++) {
        const int row = bm + ty * 4 + i;
#pragma unroll
        for (int j = 0; j < 6; j++) {
            part[((size_t)ks * LL + row) * NXDBL + tx * 6 + j] = acc[i][j];
        }
    }
}

__global__ __launch_bounds__(256) void gemm2_reduce(const float* __restrict__ part,
                                                    float* __restrict__ xdbl) {
    const int gid = blockIdx.x * 256 + threadIdx.x;
    if (gid < LL * NXDBL) {
        float s = 0.f;
#pragma unroll
        for (int ks = 0; ks < KSPLIT; ks++) s += part[(size_t)ks * LL * NXDBL + gid];
        xdbl[gid] = s;
    }
}

// ---------------- scan phase 1: per-chunk composition, 16 states/thread ---------
__global__ __launch_bounds__(256) void scan_phase1(const float* __restrict__ dt,
                                                   const float* __restrict__ xs,
                                                   const float* __restrict__ xdbl,
                                                   const float* __restrict__ A_log,
                                                   float* __restrict__ chA,
                                                   float* __restrict__ chB) {
    const int g = blockIdx.x * 256 + threadIdx.x;
    const int d = g & (DI - 1);
    const int c = g >> 11;
    float An2[NS], ap[NS], bc[NS];
    {
        float al[NS];
#pragma unroll
        for (int q = 0; q < 4; q++)
            *(float4*)&al[q * 4] = *(const float4*)&A_log[d * NS + q * 4];
#pragma unroll
        for (int n = 0; n < NS; n++) {
            An2[n] = -__expf(al[n]) * 1.44269504f;
            ap[n] = 1.f;
            bc[n] = 0.f;
        }
    }
    const int l0 = c * CHLEN;
    for (int l = l0; l < l0 + CHLEN; ++l) {
        const float dtv = dt[(size_t)l * DI + d];
        const float xsv = xs[(size_t)l * DI + d];
        const float dx = dtv * xsv;
        float bv[NS];
#pragma unroll
        for (int q = 0; q < 4; q++)
            *(float4*)&bv[q * 4] = *(const float4*)&xdbl[(size_t)l * NXDBL + DTR + q * 4];
#pragma unroll
        for (int n = 0; n < NS; n++) {
            const float al = __builtin_amdgcn_exp2f(dtv * An2[n]);
            ap[n] *= al;
            bc[n] = fmaf(al, bc[n], dx * bv[n]);
        }
    }
    const size_t o = ((size_t)c * DI + d) * NS;
#pragma unroll
    for (int q = 0; q < 4; q++) {
        *(float4*)&chA[o + q * 4] = *(float4*)&ap[q * 4];
        *(float4*)&chB[o + q * 4] = *(float4*)&bc[q * 4];
    }
}

// ---------------- scan phase 2: serial prefix over chunks (h0 in-place in chA) ---
__global__ __launch_bounds__(256) void scan_phase2(float* __restrict__ chA,
                                                   const float* __restrict__ chB,
                                                   float* __restrict__ hT_out) {
    const int t = blockIdx.x * 256 + threadIdx.x;  // 0..DI*NS-1
    float h = 0.f;
#pragma unroll 4
    for (int c = 0; c < NCHUNK; ++c) {
        const size_t o = (size_t)c * DI * NS + t;
        const float a = chA[o];
        const float b = chB[o];
        chA[o] = h;  // h0 for chunk c, overwrites a (already consumed)
        h = fmaf(a, h, b);
    }
    hT_out[t] = h;
}

// ---------------- scan phase 3: re-scan with h0, fused y epilogue (bf16 y) -------
__global__ __launch_bounds__(256) void scan_phase3(const float* __restrict__ dt,
                                                   const float* __restrict__ xs,
                                                   const float* __restrict__ xdbl,
                                                   const float* __restrict__ A_log,
                                                   const float* __restrict__ h0,
                                                   const float* __restrict__ Dw,
                                                   const float* __restrict__ res,
                                                   u16* __restrict__ yb) {
    const int g = blockIdx.x * 256 + threadIdx.x;
    const int d = g & (DI - 1);
    const int c = g >> 11;
    float An2[NS], h[NS];
    {
        float al[NS];
#pragma unroll
        for (int q = 0; q < 4; q++)
            *(float4*)&al[q * 4] = *(const float4*)&A_log[d * NS + q * 4];
#pragma unroll
        for (int n = 0; n < NS; n++) An2[n] = -__expf(al[n]) * 1.44269504f;
    }
    const size_t ho = ((size_t)c * DI + d) * NS;
#pragma unroll
    for (int q = 0; q < 4; q++) *(float4*)&h[q * 4] = *(const float4*)&h0[ho + q * 4];
    const float Dd = Dw[d];
    const int l0 = c * CHLEN;
    for (int l = l0; l < l0 + CHLEN; ++l) {
        const float dtv = dt[(size_t)l * DI + d];
        const float xsv = xs[(size_t)l * DI + d];
        const float resv = res[(size_t)l * DI + d];
        const float dx = dtv * xsv;
        float bv[NS], cv[NS];
#pragma unroll
        for (int q = 0; q < 4; q++) {
            *(float4*)&bv[q * 4] = *(const float4*)&xdbl[(size_t)l * NXDBL + DTR + q * 4];
            *(float4*)&cv[q * 4] =
                *(const float4*)&xdbl[(size_t)l * NXDBL + DTR + NS + q * 4];
        }
#pragma unroll
        for (int n = 0; n < NS; n++) {
            const float al = __builtin_amdgcn_exp2f(dtv * An2[n]);
            h[n] = fmaf(al, h[n], dx * bv[n]);
        }
        float y0 = 0.f, y1 = 0.f, y2 = 0.f, y3 = 0.f;
#pragma unroll
        for (int n = 0; n < NS; n += 4) {
            y0 = fmaf(h[n + 0], cv[n + 0], y0);
            y1 = fmaf(h[n + 1], cv[n + 1], y1);
            y2 = fmaf(h[n + 2], cv[n + 2], y2);
            y3 = fmaf(h[n + 3], cv[n + 3], y3);
        }
        float yv = ((y0 + y1) + (y2 + y3)) + xsv * Dd;
        yv *= siluf_(resv);
        yb[(size_t)l * DI + d] = f2b(yv);
    }
}

extern "C" void kernel_launch(void* const* d_in, const int* in_sizes, int n_in,
                              void* d_out, int out_size, void* d_ws, size_t ws_size,
                              hipStream_t stream) {
    const float* x = (const float*)d_in[0];
    const float* W_in = (const float*)d_in[1];
    const float* conv_w = (const float*)d_in[2];
    const float* conv_b = (const float*)d_in[3];
    const float* W_x = (const float*)d_in[4];
    const float* W_dt = (const float*)d_in[5];
    const float* b_dt = (const float*)d_in[6];
    const float* A_log = (const float*)d_in[7];
    const float* Dw = (const float*)d_in[8];
    const float* W_out = (const float*)d_in[9];
    float* out = (float*)d_out;

    float* ws = (float*)d_ws;
    float* xc = ws;                    // [0, 4194304)        L*DI f32 ; later yb (bf16)
    float* res = ws + 4194304;         // [4194304, 8388608)  L*DI f32 ; later GEMM4 partials
    float* xs = ws + 8388608;          // [8388608, 12582912) L*DI f32
    float* dt = ws + 12582912;         // [12582912,16777216) L*DI f32 ; earlier W_inT_b
    float* xdbl = ws + 16777216;       // [16777216,16973824) L*96 f32
    float* chA = ws + 16973824;        // [16973824,19070976) NCHUNK*DI*NS f32 (->h0)
    float* chB = ws + 19070976;        // [19070976,21168128) NCHUNK*DI*NS f32
                                       //   also hosts: xb, part, W_outT_b (disjoint lives)
    // aliased buffers:
    u16* xb = (u16*)chB;          // L*DM bf16 — live convert->gemm1
    float* part = chB;            // 8*L*96 f32 — live gemm2_splitk->reduce
    u16* W_outT_b = (u16*)chB;    // DM*DI bf16 — live after phase2
    u16* W_inT_b = (u16*)dt;      // 2DI*DM bf16 — dead before dt written
    u16* yb = (u16*)xc;           // L*DI bf16 — xc dead after conv_silu
    float* g4part = res;          // 2 * LL*DM f32 = 16MB — res dead after phase3

    // 1) bf16 converts for GEMM1
    convert_plain<<<(LL * DM) / 1024, 256, 0, stream>>>(x, xb);
    convert_T<<<dim3(2 * DI / 32, DM / 32), 256, 0, stream>>>(W_in, W_inT_b, DM, 2 * DI);
    // 2) x_and_res = x @ W_in  (bf16 MFMA) -> xc, res
    gemm_mfma<1, DM / 32><<<dim3(2 * DI / 128, LL / 128), 256, 0, stream>>>(
        xb, W_inT_b, xc, res, LL, 2 * DI, DM);
    // 3) conv + silu -> xs
    conv_silu<<<(LL * DI) / 256, 256, 0, stream>>>(xc, conv_w, conv_b, xs);
    // 4) x_dbl = xs @ W_x (split-K + reduce; part overwrites xb — dead)
    gemm2_splitk<<<dim3(LL / 64, KSPLIT), 256, 0, stream>>>(xs, W_x, part);
    gemm2_reduce<<<(LL * NXDBL + 255) / 256, 256, 0, stream>>>(part, xdbl);
    // 5) dt = softplus(dt_r @ W_dt + b_dt)  (fp32 128^2 8x8; overwrites W_inT_b — dead)
    gemm128_dt<<<dim3(DI / 128, LL / 128), 256, 0, stream>>>(xdbl, W_dt, b_dt, dt,
                                                             DI, DTR, NXDBL);
    // 6) chunked scan (chB overwrites part — dead)
    scan_phase1<<<(DI * NCHUNK) / 256, 256, 0, stream>>>(dt, xs, xdbl, A_log, chA, chB);
    scan_phase2<<<(DI * NS) / 256, 256, 0, stream>>>(chA, chB, out + (size_t)LL * DM);
    // 7) W_out convert (chB dead after phase2) + scan phase 3 -> yb (bf16)
    convert_T<<<dim3(DM / 32, DI / 32), 256, 0, stream>>>(W_out, W_outT_b, DI, DM);
    scan_phase3<<<(DI * NCHUNK) / 256, 256, 0, stream>>>(dt, xs, xdbl, A_log, chA, Dw,
                                                         res, yb);
    // 8) out = y @ W_out (bf16 MFMA, split-K=2 over blockIdx.z; res now dead)
    gemm_mfma<0, DI / 64><<<dim3(DM / 128, LL / 128, 2), 256, 0, stream>>>(
        yb, W_outT_b, g4part, nullptr, LL, DM, DI);
    sum2<<<(LL * DM) / 1024, 256, 0, stream>>>(g4part, out, LL * DM);
}

// Round 8
// 179.835 us; speedup vs baseline: 3.1041x; 1.1217x over previous
//
#include <hip/hip_runtime.h>
#include <math.h>

#define DM 1024
#define DI 2048
#define NS 16
#define DTR 64
#define LL 2048
#define NXDBL 96      // DTR + 2*NS
#define NCHUNK 64
#define CHLEN 32      // LL / NCHUNK

typedef unsigned short u16;
typedef __attribute__((ext_vector_type(8))) short short8;
typedef __attribute__((ext_vector_type(4))) float f32x4;

__device__ __forceinline__ float sigmoidf_(float x) { return 1.f / (1.f + __expf(-x)); }
__device__ __forceinline__ float siluf_(float x) { return x * sigmoidf_(x); }
__device__ __forceinline__ float softplus_fast(float x) {
    return fmaxf(x, 0.f) + __logf(1.f + __expf(-fabsf(x)));
}
__device__ __forceinline__ u16 f2b(float f) {  // fp32 -> bf16 RNE
    unsigned u = __float_as_uint(f);
    return (u16)((u + 0x7FFFu + ((u >> 16) & 1u)) >> 16);
}

// ---------------- fp32 -> bf16 plain convert (4 elems/thread) -----------------
__global__ __launch_bounds__(256) void convert_plain(const float* __restrict__ src,
                                                     u16* __restrict__ dst) {
    const int i = (blockIdx.x * 256 + threadIdx.x) * 4;
    float4 v = *(const float4*)&src[i];
    u16 o[4] = {f2b(v.x), f2b(v.y), f2b(v.z), f2b(v.w)};
    *(ushort4*)&dst[i] = *(ushort4*)o;
}

// ---------------- fp32 [R][C] -> bf16 [C][R] transpose convert -----------------
__global__ __launch_bounds__(256) void convert_T(const float* __restrict__ src,
                                                 u16* __restrict__ dst, int R, int C) {
    __shared__ float t[32][33];
    const int tx = threadIdx.x & 31, ty = threadIdx.x >> 5;  // ty 0..7
    const int c0 = blockIdx.x * 32, r0 = blockIdx.y * 32;
#pragma unroll
    for (int i = 0; i < 4; i++)
        t[ty + i * 8][tx] = src[(size_t)(r0 + ty + i * 8) * C + c0 + tx];
    __syncthreads();
#pragma unroll
    for (int i = 0; i < 4; i++)
        dst[(size_t)(c0 + ty + i * 8) * R + r0 + tx] = f2b(t[tx][ty + i * 8]);
}

__global__ __launch_bounds__(256) void fill_zero_u16(u16* __restrict__ p, int n) {
    const int i = blockIdx.x * 256 + threadIdx.x;
    if (i < n) p[i] = 0;
}

// ---------------- bf16 MFMA GEMM: C[M][N] = A[M][K] @ Bt[N][K]^T -----------------
// 128x128 tile, BK=32, K = NSTEPS*32. 3-buffer LDS pipeline, prefetch distance 2,
// counted s_waitcnt vmcnt(N) + raw s_barrier. LDS k-group XOR swizzle
// (kg' = kg ^ ((row>>1)&3)) applied on the per-lane GLOBAL source (write side)
// and on the ds_read offset (read side); LDS stays linear for global_load_lds.
// EPI==1: split cols [0,DI)->C0, [DI,2DI)->C1, both ld=DI.
// EPI==0: fp32 partial to C0 + blockIdx.z*M*N (split-K over gridDim.z).
#define WAITV(N) asm volatile("s_waitcnt vmcnt(" #N ")" ::: "memory")
template <int EPI, int NSTEPS>
__global__ __launch_bounds__(256) void gemm_mfma(const u16* __restrict__ A,
                                                 const u16* __restrict__ Bt,
                                                 float* __restrict__ C0,
                                                 float* __restrict__ C1,
                                                 int M, int N, int lda) {
    __shared__ u16 As[3][128 * 32];
    __shared__ u16 Bs[3][128 * 32];
    const int tid = threadIdx.x;
    const int lane = tid & 63;
    const int wave = tid >> 6;
    const int bm = blockIdx.y * 128, bn = blockIdx.x * 128;
    const int wr = wave >> 1, wc = wave & 1;
    const int k_off = blockIdx.z * (NSTEPS * 32);

    f32x4 acc[4][4];
#pragma unroll
    for (int m = 0; m < 4; m++)
#pragma unroll
        for (int n = 0; n < 4; n++) acc[m][n] = (f32x4)0.f;

    // staging: thread tid -> (row = tid>>2, kg = tid&3), LDS linear at tid*16B.
    // source k-group is swizzled: kg_src = kg ^ ((row>>1)&3)
    const int srow = tid >> 2;
    const int swz = (tid >> 3) & 3;                    // (srow>>1)&3
    const int skel = (((tid & 3) ^ swz) << 3);         // swizzled k elem offset
    const u16* Ag0 = A + (size_t)(bm + srow) * lda + k_off + skel;
    const u16* Ag1 = A + (size_t)(bm + 64 + srow) * lda + k_off + skel;
    const u16* Bg0 = Bt + (size_t)(bn + srow) * lda + k_off + skel;
    const u16* Bg1 = Bt + (size_t)(bn + 64 + srow) * lda + k_off + skel;
    u16* Asl = &As[0][0] + tid * 8;
    u16* Bsl = &Bs[0][0] + tid * 8;

    // fragment read offsets (u16 units), same swizzle on the kg index
    const int rsw = (lane >> 1) & 3;                   // row bits 1-2 (from lane&15)
    const int arow = (wr * 64 + (lane & 15)) * 32 + (((lane >> 4) ^ rsw) << 3);
    const int brow = (wc * 64 + (lane & 15)) * 32 + (((lane >> 4) ^ rsw) << 3);

#define STAGE(buf, ks)                                                               \
    do {                                                                             \
        __builtin_amdgcn_global_load_lds(                                            \
            (const __attribute__((address_space(1))) unsigned*)(Ag0 + (ks)),         \
            (__attribute__((address_space(3))) unsigned*)(Asl + (buf) * 4096),       \
            16, 0, 0);                                                               \
        __builtin_amdgcn_global_load_lds(                                            \
            (const __attribute__((address_space(1))) unsigned*)(Ag1 + (ks)),         \
            (__attribute__((address_space(3))) unsigned*)(Asl + (buf) * 4096 + 2048),\
            16, 0, 0);                                                               \
        __builtin_amdgcn_global_load_lds(                                            \
            (const __attribute__((address_space(1))) unsigned*)(Bg0 + (ks)),         \
            (__attribute__((address_space(3))) unsigned*)(Bsl + (buf) * 4096),       \
            16, 0, 0);                                                               \
        __builtin_amdgcn_global_load_lds(                                            \
            (const __attribute__((address_space(1))) unsigned*)(Bg1 + (ks)),         \
            (__attribute__((address_space(3))) unsigned*)(Bsl + (buf) * 4096 + 2048),\
            16, 0, 0);                                                               \
    } while (0)

#define COMPUTE(buf)                                                                 \
    do {                                                                             \
        short8 av[4], bv[4];                                                         \
        _Pragma("unroll") for (int m = 0; m < 4; m++)                                \
            av[m] = *(const short8*)&As[buf][arow + m * 512];                        \
        _Pragma("unroll") for (int n = 0; n < 4; n++)                                \
            bv[n] = *(const short8*)&Bs[buf][brow + n * 512];                        \
        _Pragma("unroll") for (int m = 0; m < 4; m++)                                \
            _Pragma("unroll") for (int n = 0; n < 4; n++)                            \
                acc[m][n] = __builtin_amdgcn_mfma_f32_16x16x32_bf16(av[m], bv[n],    \
                                                                    acc[m][n], 0, 0, 0); \
    } while (0)

    STAGE(0, 0);
    if (NSTEPS > 1) STAGE(1, 32);
#pragma unroll
    for (int s = 0; s < NSTEPS; ++s) {
        if (s + 2 < NSTEPS) {
            STAGE((s + 2) % 3, (s + 2) * 32);
            WAITV(8);                      // oldest 4 (tile s) complete; 8 in flight
        } else if (s + 1 < NSTEPS) {
            WAITV(4);
        } else {
            WAITV(0);
        }
        __builtin_amdgcn_s_barrier();      // tile s visible to all waves
        COMPUTE(s % 3);
        __builtin_amdgcn_s_barrier();      // reads done before buf reuse
    }
#undef STAGE
#undef COMPUTE

    const int crow0 = bm + wr * 64 + (lane >> 4) * 4;
    const int ccol0 = bn + wc * 64 + (lane & 15);
    float* C0z = C0 + (size_t)blockIdx.z * M * N;
#pragma unroll
    for (int m = 0; m < 4; m++)
#pragma unroll
        for (int n = 0; n < 4; n++) {
            const int col = ccol0 + n * 16;
#pragma unroll
            for (int r = 0; r < 4; r++) {
                const int row = crow0 + m * 16 + r;
                const float v = acc[m][n][r];
                if (EPI == 1) {
                    if (col < DI)
                        C0[(size_t)row * DI + col] = v;
                    else
                        C1[(size_t)row * DI + col - DI] = v;
                } else {
                    C0z[(size_t)row * N + col] = v;
                }
            }
        }
}

// ---------------- fp32 GEMM 128x128 tile, 8x8 micro, BK=16: dt path (K=64) -------
__global__ __launch_bounds__(256) void gemm128_dt(const float* __restrict__ A,
                                                  const float* __restrict__ B,
                                                  const float* __restrict__ bias,
                                                  float* __restrict__ C,
                                                  int N, int K, int lda) {
    __shared__ float As[16][128];
    __shared__ float Bs[16][128];
    const int tid = threadIdx.x;
    const int bm = blockIdx.y * 128, bn = blockIdx.x * 128;
    const int ty = tid >> 4, tx = tid & 15;
    float acc[8][8];
#pragma unroll
    for (int i = 0; i < 8; i++)
#pragma unroll
        for (int j = 0; j < 8; j++) acc[i][j] = 0.f;

    const int ar = tid >> 2, ak = (tid & 3) << 2;
    const int bk = tid >> 5, bc = (tid & 31) << 2;

    for (int k0 = 0; k0 < K; k0 += 16) {
        float4 a0 = *(const float4*)&A[(size_t)(bm + ar) * lda + k0 + ak];
        float4 a1 = *(const float4*)&A[(size_t)(bm + ar + 64) * lda + k0 + ak];
        float4 b0 = *(const float4*)&B[(size_t)(k0 + bk) * N + bn + bc];
        float4 b1 = *(const float4*)&B[(size_t)(k0 + bk + 8) * N + bn + bc];
        __syncthreads();
        As[ak + 0][ar] = a0.x; As[ak + 1][ar] = a0.y;
        As[ak + 2][ar] = a0.z; As[ak + 3][ar] = a0.w;
        As[ak + 0][ar + 64] = a1.x; As[ak + 1][ar + 64] = a1.y;
        As[ak + 2][ar + 64] = a1.z; As[ak + 3][ar + 64] = a1.w;
        *(float4*)&Bs[bk][bc] = b0;
        *(float4*)&Bs[bk + 8][bc] = b1;
        __syncthreads();
#pragma unroll
        for (int k = 0; k < 16; k++) {
            float a[8], b[8];
            *(float4*)&a[0] = *(const float4*)&As[k][ty * 8];
            *(float4*)&a[4] = *(const float4*)&As[k][ty * 8 + 4];
            *(float4*)&b[0] = *(const float4*)&Bs[k][tx * 8];
            *(float4*)&b[4] = *(const float4*)&Bs[k][tx * 8 + 4];
#pragma unroll
            for (int i = 0; i < 8; i++)
#pragma unroll
                for (int j = 0; j < 8; j++) acc[i][j] = fmaf(a[i], b[j], acc[i][j]);
        }
    }
#pragma unroll
    for (int i = 0; i < 8; i++) {
        const int row = bm + ty * 8 + i;
#pragma unroll
        for (int j = 0; j < 8; j += 4) {
            const int col = bn + tx * 8 + j;
            const float4 bi = *(const float4*)&bias[col];
            float4 v = make_float4(softplus_fast(acc[i][j] + bi.x),
                                   softplus_fast(acc[i][j + 1] + bi.y),
                                   softplus_fast(acc[i][j + 2] + bi.z),
                                   softplus_fast(acc[i][j + 3] + bi.w));
            *(float4*)&C[(size_t)row * N + col] = v;
        }
    }
}

// ---------------- sum of 2 split-K partials -----------------
__global__ __launch_bounds__(256) void sum2(const float* __restrict__ p,
                                            float* __restrict__ out, int n) {
    const int i = (blockIdx.x * 256 + threadIdx.x) * 4;
    float4 a = *(const float4*)&p[i];
    float4 b = *(const float4*)&p[(size_t)n + i];
    *(float4*)&out[i] = make_float4(a.x + b.x, a.y + b.y, a.z + b.z, a.w + b.w);
}

// ---------------- reduce 16 split-K partials [z][L][128] -> xdbl [L][96] ---------
__global__ __launch_bounds__(256) void g2reduce(const float* __restrict__ part,
                                                float* __restrict__ xdbl) {
    const int gid = blockIdx.x * 256 + threadIdx.x;
    if (gid < LL * NXDBL) {
        const int row = gid / NXDBL;
        const int col = gid - row * NXDBL;
        float s = 0.f;
#pragma unroll
        for (int z = 0; z < 16; z++) s += part[((size_t)z * LL + row) * 128 + col];
        xdbl[gid] = s;
    }
}

// ---------------- conv (k=4, causal) + silu -> xs (f32) + xs_b (bf16) ------------
__global__ __launch_bounds__(256) void conv_silu(const float* __restrict__ xc,
                                                 const float* __restrict__ cw,
                                                 const float* __restrict__ cb,
                                                 float* __restrict__ xs,
                                                 u16* __restrict__ xsb) {
    const int gid = blockIdx.x * 256 + threadIdx.x;  // l*DI + d
    const int l = gid >> 11;
    const int d = gid & (DI - 1);
    const float4 w = *(const float4*)&cw[d * 4];
    float acc = cb[d];
    const float wj[4] = {w.x, w.y, w.z, w.w};
#pragma unroll
    for (int j = 0; j < 4; j++) {
        const int li = l + j - 3;
        if (li >= 0) acc = fmaf(xc[(size_t)li * DI + d], wj[j], acc);
    }
    const float s = siluf_(acc);
    xs[gid] = s;
    xsb[gid] = f2b(s);
}

// ---------------- scan phase 1: per-chunk composition, 16 states/thread ---------
__global__ __launch_bounds__(256) void scan_phase1(const float* __restrict__ dt,
                                                   const float* __restrict__ xs,
                                                   const float* __restrict__ xdbl,
                                                   const float* __restrict__ A_log,
                                                   float* __restrict__ chA,
                                                   float* __restrict__ chB) {
    const int g = blockIdx.x * 256 + threadIdx.x;
    const int d = g & (DI - 1);
    const int c = g >> 11;
    float An2[NS], ap[NS], bc[NS];
    {
        float al[NS];
#pragma unroll
        for (int q = 0; q < 4; q++)
            *(float4*)&al[q * 4] = *(const float4*)&A_log[d * NS + q * 4];
#pragma unroll
        for (int n = 0; n < NS; n++) {
            An2[n] = -__expf(al[n]) * 1.44269504f;
            ap[n] = 1.f;
            bc[n] = 0.f;
        }
    }
    const int l0 = c * CHLEN;
    for (int l = l0; l < l0 + CHLEN; ++l) {
        const float dtv = dt[(size_t)l * DI + d];
        const float xsv = xs[(size_t)l * DI + d];
        const float dx = dtv * xsv;
        float bv[NS];
#pragma unroll
        for (int q = 0; q < 4; q++)
            *(float4*)&bv[q * 4] = *(const float4*)&xdbl[(size_t)l * NXDBL + DTR + q * 4];
#pragma unroll
        for (int n = 0; n < NS; n++) {
            const float al = __builtin_amdgcn_exp2f(dtv * An2[n]);
            ap[n] *= al;
            bc[n] = fmaf(al, bc[n], dx * bv[n]);
        }
    }
    const size_t o = ((size_t)c * DI + d) * NS;
#pragma unroll
    for (int q = 0; q < 4; q++) {
        *(float4*)&chA[o + q * 4] = *(float4*)&ap[q * 4];
        *(float4*)&chB[o + q * 4] = *(float4*)&bc[q * 4];
    }
}

// ---------------- scan phase 2: serial prefix over chunks (h0 in-place in chA) ---
__global__ __launch_bounds__(256) void scan_phase2(float* __restrict__ chA,
                                                   const float* __restrict__ chB,
                                                   float* __restrict__ hT_out) {
    const int t = blockIdx.x * 256 + threadIdx.x;  // 0..DI*NS-1
    float h = 0.f;
#pragma unroll 4
    for (int c = 0; c < NCHUNK; ++c) {
        const size_t o = (size_t)c * DI * NS + t;
        const float a = chA[o];
        const float b = chB[o];
        chA[o] = h;
        h = fmaf(a, h, b);
    }
    hT_out[t] = h;
}

// ---------------- scan phase 3: re-scan with h0, fused y epilogue (bf16 y) -------
__global__ __launch_bounds__(256) void scan_phase3(const float* __restrict__ dt,
                                                   const float* __restrict__ xs,
                                                   const float* __restrict__ xdbl,
                                                   const float* __restrict__ A_log,
                                                   const float* __restrict__ h0,
                                                   const float* __restrict__ Dw,
                                                   const float* __restrict__ res,
                                                   u16* __restrict__ yb) {
    const int g = blockIdx.x * 256 + threadIdx.x;
    const int d = g & (DI - 1);
    const int c = g >> 11;
    float An2[NS], h[NS];
    {
        float al[NS];
#pragma unroll
        for (int q = 0; q < 4; q++)
            *(float4*)&al[q * 4] = *(const float4*)&A_log[d * NS + q * 4];
#pragma unroll
        for (int n = 0; n < NS; n++) An2[n] = -__expf(al[n]) * 1.44269504f;
    }
    const size_t ho = ((size_t)c * DI + d) * NS;
#pragma unroll
    for (int q = 0; q < 4; q++) *(float4*)&h[q * 4] = *(const float4*)&h0[ho + q * 4];
    const float Dd = Dw[d];
    const int l0 = c * CHLEN;
    for (int l = l0; l < l0 + CHLEN; ++l) {
        const float dtv = dt[(size_t)l * DI + d];
        const float xsv = xs[(size_t)l * DI + d];
        const float resv = res[(size_t)l * DI + d];
        const float dx = dtv * xsv;
        float bv[NS], cv[NS];
#pragma unroll
        for (int q = 0; q < 4; q++) {
            *(float4*)&bv[q * 4] = *(const float4*)&xdbl[(size_t)l * NXDBL + DTR + q * 4];
            *(float4*)&cv[q * 4] =
                *(const float4*)&xdbl[(size_t)l * NXDBL + DTR + NS + q * 4];
        }
#pragma unroll
        for (int n = 0; n < NS; n++) {
            const float al = __builtin_amdgcn_exp2f(dtv * An2[n]);
            h[n] = fmaf(al, h[n], dx * bv[n]);
        }
        float y0 = 0.f, y1 = 0.f, y2 = 0.f, y3 = 0.f;
#pragma unroll
        for (int n = 0; n < NS; n += 4) {
            y0 = fmaf(h[n + 0], cv[n + 0], y0);
            y1 = fmaf(h[n + 1], cv[n + 1], y1);
            y2 = fmaf(h[n + 2], cv[n + 2], y2);
            y3 = fmaf(h[n + 3], cv[n + 3], y3);
        }
        float yv = ((y0 + y1) + (y2 + y3)) + xsv * Dd;
        yv *= siluf_(resv);
        yb[(size_t)l * DI + d] = f2b(yv);
    }
}

extern "C" void kernel_launch(void* const* d_in, const int* in_sizes, int n_in,
                              void* d_out, int out_size, void* d_ws, size_t ws_size,
                              hipStream_t stream) {
    const float* x = (const float*)d_in[0];
    const float* W_in = (const float*)d_in[1];
    const float* conv_w = (const float*)d_in[2];
    const float* conv_b = (const float*)d_in[3];
    const float* W_x = (const float*)d_in[4];
    const float* W_dt = (const float*)d_in[5];
    const float* b_dt = (const float*)d_in[6];
    const float* A_log = (const float*)d_in[7];
    const float* Dw = (const float*)d_in[8];
    const float* W_out = (const float*)d_in[9];
    float* out = (float*)d_out;

    // Flat workspace map (ws ~268 MB; no aliasing), offsets in floats:
    // sizes: L*DI bf16 buffers are 2097152 float-equivalents (8 MB) — r7 bug was 1048576.
    float* ws = (float*)d_ws;
    float* xc       = ws;                     // L*DI f32      [0,        4194304)
    float* res      = ws + 4194304;           // L*DI f32      [4194304,  8388608)
    float* xs       = ws + 8388608;           // L*DI f32      [8388608,  12582912)
    float* dt       = ws + 12582912;          // L*DI f32      [12582912, 16777216)
    float* xdbl     = ws + 16777216;          // L*96 f32      (196608)
    float* chA      = ws + 16973824;          // NCHUNK*DI*NS  (2097152, ->h0)
    float* chB      = ws + 19070976;          // NCHUNK*DI*NS  (2097152)
    u16*   xb       = (u16*)(ws + 21168128);  // L*DM bf16     (1048576 f)
    u16*   W_inT_b  = (u16*)(ws + 22216704);  // 2DI*DM bf16   (2097152 f)
    u16*   W_outT_b = (u16*)(ws + 24313856);  // DM*DI bf16    (1048576 f)
    u16*   xs_b     = (u16*)(ws + 25362432);  // L*DI bf16     (2097152 f)
    u16*   W_xT_pad = (u16*)(ws + 27459584);  // 128*DI bf16   (131072 f)
    float* g2part   = ws + 27590656;          // 16*L*128 f32  (4194304 f)
    float* g4part   = ws + 31784960;          // 2*L*DM f32    (4194304 f)
    u16*   yb       = (u16*)(ws + 35979264);  // L*DI bf16     (2097152 f)
    // total 38076416 floats = 152.3 MB

    // 1) bf16 converts for GEMM1
    convert_plain<<<(LL * DM) / 1024, 256, 0, stream>>>(x, xb);
    convert_T<<<dim3(2 * DI / 32, DM / 32), 256, 0, stream>>>(W_in, W_inT_b, DM, 2 * DI);
    // 2) x_and_res = x @ W_in  (bf16 MFMA) -> xc, res
    gemm_mfma<1, DM / 32><<<dim3(2 * DI / 128, LL / 128), 256, 0, stream>>>(
        xb, W_inT_b, xc, res, LL, 2 * DI, DM);
    // 3) conv + silu -> xs (f32) + xs_b (bf16)
    conv_silu<<<(LL * DI) / 256, 256, 0, stream>>>(xc, conv_w, conv_b, xs, xs_b);
    // 4) W_x -> [96][DI] bf16, rows 96..127 zeroed
    fill_zero_u16<<<(32 * DI + 255) / 256, 256, 0, stream>>>(W_xT_pad + 96 * DI, 32 * DI);
    convert_T<<<dim3(NXDBL / 32, DI / 32), 256, 0, stream>>>(W_x, W_xT_pad, DI, NXDBL);
    // 5) x_dbl = xs @ W_x  (bf16 MFMA, split-K=16 over z, N padded to 128)
    gemm_mfma<0, 4><<<dim3(1, LL / 128, 16), 256, 0, stream>>>(
        xs_b, W_xT_pad, g2part, nullptr, LL, 128, DI);
    g2reduce<<<(LL * NXDBL + 255) / 256, 256, 0, stream>>>(g2part, xdbl);
    // 6) dt = softplus(dt_r @ W_dt + b_dt)  (fp32 128^2 8x8)
    gemm128_dt<<<dim3(DI / 128, LL / 128), 256, 0, stream>>>(xdbl, W_dt, b_dt, dt,
                                                             DI, DTR, NXDBL);
    // 7) chunked scan
    scan_phase1<<<(DI * NCHUNK) / 256, 256, 0, stream>>>(dt, xs, xdbl, A_log, chA, chB);
    scan_phase2<<<(DI * NS) / 256, 256, 0, stream>>>(chA, chB, out + (size_t)LL * DM);
    // 8) W_out convert + scan phase 3 -> yb (bf16)
    convert_T<<<dim3(DM / 32, DI / 32), 256, 0, stream>>>(W_out, W_outT_b, DI, DM);
    scan_phase3<<<(DI * NCHUNK) / 256, 256, 0, stream>>>(dt, xs, xdbl, A_log, chA, Dw,
                                                         res, yb);
    // 9) out = y @ W_out (bf16 MFMA, split-K=2 over z)
    gemm_mfma<0, DI / 64><<<dim3(DM / 128, LL / 128, 2), 256, 0, stream>>>(
        yb, W_outT_b, g4part, nullptr, LL, DM, DI);
    sum2<<<(LL * DM) / 1024, 256, 0, stream>>>(g4part, out, LL * DM);
}